// Round 2
// baseline (841.791 us; speedup 1.0000x reference)
//
#include <hip/hip_runtime.h>

// Hgru1: q=silu((x@Wq1)@Wq2); a=sig(sig((x@Wk1)@Wk2)); v=x@Wv;
// h_t = a_t h_{t-1} + (1-a_t) v_t ; out = RMSNorm(q*h)*nw @ Wo
// B=4 N=2048 E=2048 HD=128 E2=4096, M=B*N=8192
//
// ws layout (156 MiB total; lifetimes overlaid):
//   R0 [0,64M):   X(33.5M)+WVT(16.8M)+WQ1T+WK1T  -->  AA (a, then gn) overlays
//   R1 [64M,128M): VV (v -> h -> g, all in place)
//   R2 [128M+):   T1,T2,WQ2T,WK2T,WOT,S_P,S_H,HIN

typedef unsigned short u16;
typedef __attribute__((ext_vector_type(4))) float f32x4;
typedef __attribute__((ext_vector_type(8))) __bf16 bf16x8;
typedef __attribute__((ext_vector_type(8))) u16 u16x8;
typedef __attribute__((ext_vector_type(4))) unsigned int u32x4;

__device__ __forceinline__ float bf2f(u16 u) {
  unsigned int i = ((unsigned int)u) << 16;
  return __builtin_bit_cast(float, i);
}
__device__ __forceinline__ u16 f2bf(float f) {
  unsigned int i = __builtin_bit_cast(unsigned int, f);
  i += 0x7fffu + ((i >> 16) & 1u);   // RNE
  return (u16)(i >> 16);
}

__device__ __forceinline__ void gload_lds16(const u16* g, u16* l) {
  __builtin_amdgcn_global_load_lds(
      (const __attribute__((address_space(1))) void*)g,
      (__attribute__((address_space(3))) void*)l, 16, 0, 0);
}

// ---------------- casts ----------------
__global__ __launch_bounds__(256) void cast_kernel(const float* __restrict__ in,
                                                   u16* __restrict__ out, long n) {
  long i = ((long)blockIdx.x * 256 + threadIdx.x) * 4;
  if (i >= n) return;
  f32x4 fv = *(const f32x4*)&in[i];
  unsigned long long pk = (unsigned long long)f2bf(fv[0]) |
                          ((unsigned long long)f2bf(fv[1]) << 16) |
                          ((unsigned long long)f2bf(fv[2]) << 32) |
                          ((unsigned long long)f2bf(fv[3]) << 48);
  *(unsigned long long*)&out[i] = pk;
}

// W [R][Cc] f32 -> WT [Cc][R] bf16   (grid: (Cc/32, R/32), block (32,8))
__global__ __launch_bounds__(256) void transpose_cast(const float* __restrict__ W,
                                                      u16* __restrict__ WT, int R, int Cc) {
  __shared__ float tile[32][33];
  const int tx = threadIdx.x, ty = threadIdx.y;
  const int x = blockIdx.x * 32 + tx;
  const int ybase = blockIdx.y * 32;
#pragma unroll
  for (int i = 0; i < 32; i += 8)
    tile[ty + i][tx] = W[(size_t)(ybase + ty + i) * Cc + x];
  __syncthreads();
  const int xt = ybase + tx;
  const int ytbase = blockIdx.x * 32;
#pragma unroll
  for (int i = 0; i < 32; i += 8)
    WT[(size_t)(ytbase + ty + i) * R + xt] = f2bf(tile[tx][ty + i]);
}

// ---------------- GEMM: C[m][n] = sum_k A[m][k]*BT[n][k]  (A,BT bf16) -----
// 128x128 tile, BK=32, 4 waves (2x2), each wave 64x64 via 4x4 16x16x32 MFMA.
// EPI: 0 = bf16 store, 2 = sig(sig)->bf16, 3 = f32 store,
//      4 = in-place g = silu(acc) * h  (h read from Cv, g written back)
template <int EPI>
__global__ __launch_bounds__(256) void gemm_bt(const u16* __restrict__ A,
                                               const u16* __restrict__ BT,
                                               void* __restrict__ Cv,
                                               int M, int N, int K) {
  __shared__ __align__(16) u16 As[4096];
  __shared__ __align__(16) u16 Bs[4096];
  const int tid = threadIdx.x;
  const int lane = tid & 63;
  const int wid = tid >> 6;
  const int wr = wid >> 1, wc = wid & 1;
  const long bm = (long)blockIdx.x * 128;
  const long bn = (long)blockIdx.y * 128;

  const int sm = lane >> 2;
  const int sk = (lane & 3) << 3;
  const u16* Ag0 = A + (size_t)(bm + wid * 16 + sm) * K + sk;
  const u16* Ag1 = A + (size_t)(bm + 64 + wid * 16 + sm) * K + sk;
  const u16* Bg0 = BT + (size_t)(bn + wid * 16 + sm) * K + sk;
  const u16* Bg1 = BT + (size_t)(bn + 64 + wid * 16 + sm) * K + sk;
  u16* As0 = As + wid * 512;        // HW: wave-uniform base + lane*16B
  u16* As1 = As + 2048 + wid * 512;
  u16* Bs0 = Bs + wid * 512;
  u16* Bs1 = Bs + 2048 + wid * 512;

  f32x4 acc[4][4] = {};

  const int fra = wr * 64 + (lane & 15);  // A frag row (+mi*16)
  const int frb = wc * 64 + (lane & 15);  // B frag col (+ni*16)
  const int kg = (lane >> 4) << 3;        // same k-map for A and B (symmetric)

  for (int kk = 0; kk < K; kk += 32) {
    gload_lds16(Ag0 + kk, As0);
    gload_lds16(Ag1 + kk, As1);
    gload_lds16(Bg0 + kk, Bs0);
    gload_lds16(Bg1 + kk, Bs1);
    __syncthreads();  // compiler drains vmcnt before s_barrier
    bf16x8 af[4], bv[4];
#pragma unroll
    for (int mi = 0; mi < 4; ++mi)
      af[mi] = *reinterpret_cast<const bf16x8*>(&As[(fra + mi * 16) * 32 + kg]);
#pragma unroll
    for (int ni = 0; ni < 4; ++ni)
      bv[ni] = *reinterpret_cast<const bf16x8*>(&Bs[(frb + ni * 16) * 32 + kg]);
#pragma unroll
    for (int mi = 0; mi < 4; ++mi) {
#pragma unroll
      for (int ni = 0; ni < 4; ++ni)
        acc[mi][ni] =
            __builtin_amdgcn_mfma_f32_16x16x32_bf16(af[mi], bv[ni], acc[mi][ni], 0, 0, 0);
    }
    __syncthreads();
  }

  // C/D layout: col = lane&15, row = (lane>>4)*4 + reg   [HW-verified]
  const int r0 = wr * 64 + ((lane >> 4) << 2);
  const int c0 = wc * 64 + (lane & 15);
#pragma unroll
  for (int mi = 0; mi < 4; ++mi) {
#pragma unroll
    for (int ni = 0; ni < 4; ++ni) {
#pragma unroll
      for (int r = 0; r < 4; ++r) {
        size_t row = (size_t)(bm + r0 + mi * 16 + r);
        size_t col = (size_t)(bn + c0 + ni * 16);
        size_t idx = row * (size_t)N + col;
        float val = acc[mi][ni][r];
        if constexpr (EPI == 0) {
          ((u16*)Cv)[idx] = f2bf(val);
        } else if constexpr (EPI == 2) {  // a = sigmoid(sigmoid(raw))
          float f = 1.f / (1.f + __expf(-val));
          float aa = 1.f / (1.f + __expf(-f));
          ((u16*)Cv)[idx] = f2bf(aa);
        } else if constexpr (EPI == 3) {
          ((float*)Cv)[idx] = val;
        } else {  // EPI == 4: g = silu(acc) * h, in place over h
          float hv = bf2f(((u16*)Cv)[idx]);
          float s = 1.f / (1.f + __expf(-val));
          ((u16*)Cv)[idx] = f2bf(val * s * hv);
        }
      }
    }
  }
}

// ---------------- chunked gated scan: h_t = a_t h + (1-a_t) v_t ----------
// Partition: b in [0,4), chunk c in [0,32) of Tc=64 steps, 8 channels/thread.
// Phase A: per-chunk (p = prod a, hl = local h with h_in=0)
__global__ __launch_bounds__(256) void scan_a(const u16* __restrict__ a,
                                              const u16* __restrict__ v,
                                              float* __restrict__ S_p,
                                              float* __restrict__ S_h) {
  const int idx = blockIdx.x * 256 + threadIdx.x;  // 0..65535
  const int ch8 = idx & 511;
  const int c = (idx >> 9) & 31;
  const int b = idx >> 14;
  const int ch = ch8 << 3;
  size_t off = ((size_t)(b * 2048 + c * 64)) * 4096 + ch;
  float h[8], p[8];
#pragma unroll
  for (int j = 0; j < 8; ++j) { h[j] = 0.f; p[j] = 1.f; }
  for (int t = 0; t < 64; ++t) {
    u16x8 ua = *(const u16x8*)&a[off];
    u16x8 uv = *(const u16x8*)&v[off];
#pragma unroll
    for (int j = 0; j < 8; ++j) {
      float at = bf2f(ua[j]);
      h[j] = at * h[j] + (1.f - at) * bf2f(uv[j]);
      p[j] *= at;
    }
    off += 4096;
  }
  size_t so = (size_t)(b * 32 + c) * 4096 + ch;
#pragma unroll
  for (int j = 0; j < 8; ++j) { S_p[so + j] = p[j]; S_h[so + j] = h[j]; }
}

// Phase B: serial combine of 32 chunk summaries per (b,ch) -> h_in per chunk
__global__ __launch_bounds__(256) void scan_b(const float* __restrict__ S_p,
                                              const float* __restrict__ S_h,
                                              float* __restrict__ Hin) {
  const int idx = blockIdx.x * 256 + threadIdx.x;  // 0..16383
  const int b = idx >> 12;
  const int ch = idx & 4095;
  float H = 0.f;
  for (int c = 0; c < 32; ++c) {
    size_t so = (size_t)(b * 32 + c) * 4096 + ch;
    Hin[so] = H;
    H = S_p[so] * H + S_h[so];
  }
}

// Phase C: replay with correct h_in, write h (bf16) in place over v
__global__ __launch_bounds__(256) void scan_c(const u16* __restrict__ a,
                                              u16* __restrict__ vh,
                                              const float* __restrict__ Hin) {
  const int idx = blockIdx.x * 256 + threadIdx.x;
  const int ch8 = idx & 511;
  const int c = (idx >> 9) & 31;
  const int b = idx >> 14;
  const int ch = ch8 << 3;
  size_t so = (size_t)(b * 32 + c) * 4096 + ch;
  float h[8];
#pragma unroll
  for (int j = 0; j < 8; ++j) h[j] = Hin[so + j];
  size_t off = ((size_t)(b * 2048 + c * 64)) * 4096 + ch;
  for (int t = 0; t < 64; ++t) {
    u16x8 ua = *(const u16x8*)&a[off];
    u16x8 uv = *(const u16x8*)&vh[off];
    u16x8 out;
#pragma unroll
    for (int j = 0; j < 8; ++j) {
      float at = bf2f(ua[j]);
      h[j] = at * h[j] + (1.f - at) * bf2f(uv[j]);
      out[j] = f2bf(h[j]);
    }
    *(u16x8*)&vh[off] = out;
    off += 4096;
  }
}

// ---------------- RMSNorm over channel dim (4096), one block per row ------
__global__ __launch_bounds__(256) void rmsnorm_kernel(const u16* __restrict__ g,
                                                      const float* __restrict__ w,
                                                      u16* __restrict__ gn) {
  const size_t base = (size_t)blockIdx.x * 4096;
  const int tid = threadIdx.x;
  const int c0 = tid * 16;
  u16 vals[16];
  *(u32x4*)&vals[0] = *(const u32x4*)&g[base + c0];
  *(u32x4*)&vals[8] = *(const u32x4*)&g[base + c0 + 8];
  float f[16];
  float s = 0.f;
#pragma unroll
  for (int i = 0; i < 16; ++i) {
    f[i] = bf2f(vals[i]);
    s += f[i] * f[i];
  }
#pragma unroll
  for (int o = 32; o > 0; o >>= 1) s += __shfl_down(s, o, 64);
  __shared__ float red[4];
  if ((tid & 63) == 0) red[tid >> 6] = s;
  __syncthreads();
  float tot = red[0] + red[1] + red[2] + red[3];
  float scale = rsqrtf(tot * (1.0f / 4096.0f) + 1e-6f);
#pragma unroll
  for (int i = 0; i < 16; ++i) vals[i] = f2bf(f[i] * scale * w[c0 + i]);
  *(u32x4*)&gn[base + c0] = *(u32x4*)&vals[0];
  *(u32x4*)&gn[base + c0 + 8] = *(u32x4*)&vals[8];
}

extern "C" void kernel_launch(void* const* d_in, const int* in_sizes, int n_in,
                              void* d_out, int out_size, void* d_ws, size_t ws_size,
                              hipStream_t stream) {
  const float* x   = (const float*)d_in[0];
  const float* Wq1 = (const float*)d_in[1];
  const float* Wq2 = (const float*)d_in[2];
  const float* Wk1 = (const float*)d_in[3];
  const float* Wk2 = (const float*)d_in[4];
  const float* Wv  = (const float*)d_in[5];
  const float* Wo  = (const float*)d_in[6];
  const float* nw  = (const float*)d_in[7];

  char* ws = (char*)d_ws;
  // R0: X/WVT/WQ1T/WK1T, later overlaid by AA (a -> gn)
  u16* X    = (u16*)(ws + 0);          // 8192x2048   33554432 B
  u16* WVT  = (u16*)(ws + 33554432);   // 4096x2048   16777216 B
  u16* WQ1T = (u16*)(ws + 50331648);   // 128x2048      524288 B
  u16* WK1T = (u16*)(ws + 50855936);   // 128x2048      524288 B
  u16* AA   = (u16*)(ws + 0);          // 8192x4096 overlay (a, then gn)
  // R1
  u16* VV   = (u16*)(ws + 67108864);   // 8192x4096   (v -> h -> g in place)
  // R2
  u16* T1   = (u16*)(ws + 134217728);  // 8192x128
  u16* T2   = (u16*)(ws + 136314880);  // 8192x128
  u16* WQ2T = (u16*)(ws + 138412032);  // 4096x128
  u16* WK2T = (u16*)(ws + 139460608);  // 4096x128
  u16* WOT  = (u16*)(ws + 140509184);  // 2048x4096   16777216 B
  float* S_P = (float*)(ws + 157286400);  // 4x32x4096 f32
  float* S_H = (float*)(ws + 159383552);
  float* HIN = (float*)(ws + 161480704);  // end 163577856 (156 MiB)

  cast_kernel<<<16384, 256, 0, stream>>>(x, X, 16777216L);
  transpose_cast<<<dim3(4, 64),   dim3(32, 8), 0, stream>>>(Wq1, WQ1T, 2048, 128);
  transpose_cast<<<dim3(128, 4),  dim3(32, 8), 0, stream>>>(Wq2, WQ2T, 128, 4096);
  transpose_cast<<<dim3(4, 64),   dim3(32, 8), 0, stream>>>(Wk1, WK1T, 2048, 128);
  transpose_cast<<<dim3(128, 4),  dim3(32, 8), 0, stream>>>(Wk2, WK2T, 128, 4096);
  transpose_cast<<<dim3(128, 64), dim3(32, 8), 0, stream>>>(Wv, WVT, 2048, 4096);
  transpose_cast<<<dim3(64, 128), dim3(32, 8), 0, stream>>>(Wo, WOT, 4096, 2048);

  // X-consuming GEMMs first (X/WVT/WQ1T/WK1T die here)
  gemm_bt<0><<<dim3(64, 1),  256, 0, stream>>>(X,  WQ1T, T1, 8192, 128, 2048);
  gemm_bt<0><<<dim3(64, 1),  256, 0, stream>>>(X,  WK1T, T2, 8192, 128, 2048);
  gemm_bt<0><<<dim3(64, 32), 256, 0, stream>>>(X,  WVT,  VV, 8192, 4096, 2048);
  // a into R0 overlay
  gemm_bt<2><<<dim3(64, 32), 256, 0, stream>>>(T2, WK2T, AA, 8192, 4096, 128);

  // chunked scan: VV := h (in place)
  scan_a<<<256, 256, 0, stream>>>(AA, VV, S_P, S_H);
  scan_b<<<64, 256, 0, stream>>>(S_P, S_H, HIN);
  scan_c<<<256, 256, 0, stream>>>(AA, VV, HIN);

  // g = silu(q2) * h, in place over VV
  gemm_bt<4><<<dim3(64, 32), 256, 0, stream>>>(T1, WQ2T, VV, 8192, 4096, 128);

  // gn into R0 (a is dead)
  rmsnorm_kernel<<<8192, 256, 0, stream>>>(VV, nw, AA);

  // out = gn @ Wo
  gemm_bt<3><<<dim3(64, 16), 256, 0, stream>>>(AA, WOT, d_out, 8192, 2048, 4096);
}

// Round 6
// 674.255 us; speedup vs baseline: 1.2485x; 1.2485x over previous
//
#include <hip/hip_runtime.h>

// Hgru1: q=silu((x@Wq1)@Wq2); a=sig(sig((x@Wk1)@Wk2)); v=x@Wv;
// h_t = a_t h_{t-1} + (1-a_t) v_t ; out = RMSNorm(q*h)*nw @ Wo
// B=4 N=2048 E=2048 HD=128 E2=4096, M=B*N=8192

typedef unsigned short u16;
typedef __attribute__((ext_vector_type(4))) float f32x4;
typedef __attribute__((ext_vector_type(8))) __bf16 bf16x8;
typedef __attribute__((ext_vector_type(8))) u16 u16x8;
typedef __attribute__((ext_vector_type(4))) unsigned int u32x4;

__device__ __forceinline__ float bf2f(u16 u) {
  unsigned int i = ((unsigned int)u) << 16;
  return __builtin_bit_cast(float, i);
}
__device__ __forceinline__ u16 f2bf(float f) {
  unsigned int i = __builtin_bit_cast(unsigned int, f);
  i += 0x7fffu + ((i >> 16) & 1u);   // RNE
  return (u16)(i >> 16);
}

__device__ __forceinline__ void gload_lds16(const u16* g, u16* l) {
  __builtin_amdgcn_global_load_lds(
      (const __attribute__((address_space(1))) void*)g,
      (__attribute__((address_space(3))) void*)l, 16, 0, 0);
}

// ---------------- casts ----------------
__global__ __launch_bounds__(256) void cast_kernel(const float* __restrict__ in,
                                                   u16* __restrict__ out, long n) {
  long i = ((long)blockIdx.x * 256 + threadIdx.x) * 4;
  if (i >= n) return;
  f32x4 fv = *(const f32x4*)&in[i];
  unsigned long long pk = (unsigned long long)f2bf(fv[0]) |
                          ((unsigned long long)f2bf(fv[1]) << 16) |
                          ((unsigned long long)f2bf(fv[2]) << 32) |
                          ((unsigned long long)f2bf(fv[3]) << 48);
  *(unsigned long long*)&out[i] = pk;
}

// W [R][Cc] f32 -> WT [Cc][R] bf16   (grid: (Cc/32, R/32), block (32,8))
__global__ __launch_bounds__(256) void transpose_cast(const float* __restrict__ W,
                                                      u16* __restrict__ WT, int R, int Cc) {
  __shared__ float tile[32][33];
  const int tx = threadIdx.x, ty = threadIdx.y;
  const int x = blockIdx.x * 32 + tx;
  const int ybase = blockIdx.y * 32;
#pragma unroll
  for (int i = 0; i < 32; i += 8)
    tile[ty + i][tx] = W[(size_t)(ybase + ty + i) * Cc + x];
  __syncthreads();
  const int xt = ybase + tx;
  const int ytbase = blockIdx.x * 32;
#pragma unroll
  for (int i = 0; i < 32; i += 8)
    WT[(size_t)(ytbase + ty + i) * R + xt] = f2bf(tile[tx][ty + i]);
}

// Wo variant: WT[n][k] = Wo[k][n] * nw[k]  (folds RMSNorm weight into Wo)
__global__ __launch_bounds__(256) void transpose_cast_nw(const float* __restrict__ W,
                                                         const float* __restrict__ nw,
                                                         u16* __restrict__ WT, int R, int Cc) {
  __shared__ float tile[32][33];
  const int tx = threadIdx.x, ty = threadIdx.y;
  const int x = blockIdx.x * 32 + tx;
  const int ybase = blockIdx.y * 32;
#pragma unroll
  for (int i = 0; i < 32; i += 8)
    tile[ty + i][tx] = W[(size_t)(ybase + ty + i) * Cc + x];
  __syncthreads();
  const int xt = ybase + tx;           // k index
  const float s = nw[xt];
  const int ytbase = blockIdx.x * 32;
#pragma unroll
  for (int i = 0; i < 32; i += 8)
    WT[(size_t)(ytbase + ty + i) * R + xt] = f2bf(tile[tx][ty + i] * s);
}

// ---------------- 128x128 GEMM (2-barrier, for K=128/N=256 cases) ----------
// C[m][n] = sum_k A[m][k]*BT[n][k]; A row stride = lda.
// EPI: 0 bf16 store; 2 sig(sig)->bf16; 4 in-place g = silu(acc)*h
template <int EPI>
__global__ __launch_bounds__(256) void gemm_bt(const u16* __restrict__ A, int lda,
                                               const u16* __restrict__ BT,
                                               void* __restrict__ Cv,
                                               int M, int N, int K) {
  __shared__ __align__(16) u16 As[4096];
  __shared__ __align__(16) u16 Bs[4096];
  const int tid = threadIdx.x;
  const int lane = tid & 63;
  const int wid = tid >> 6;
  const int wr = wid >> 1, wc = wid & 1;
  const long bm = (long)blockIdx.x * 128;
  const long bn = (long)blockIdx.y * 128;

  const int sm = lane >> 2;
  const int sk = (lane & 3) << 3;
  const u16* Ag0 = A + (size_t)(bm + wid * 16 + sm) * lda + sk;
  const u16* Ag1 = A + (size_t)(bm + 64 + wid * 16 + sm) * lda + sk;
  const u16* Bg0 = BT + (size_t)(bn + wid * 16 + sm) * K + sk;
  const u16* Bg1 = BT + (size_t)(bn + 64 + wid * 16 + sm) * K + sk;
  u16* As0 = As + wid * 512;
  u16* As1 = As + 2048 + wid * 512;
  u16* Bs0 = Bs + wid * 512;
  u16* Bs1 = Bs + 2048 + wid * 512;

  f32x4 acc[4][4] = {};

  const int fra = wr * 64 + (lane & 15);
  const int frb = wc * 64 + (lane & 15);
  const int kg = (lane >> 4) << 3;

  for (int kk = 0; kk < K; kk += 32) {
    gload_lds16(Ag0 + kk, As0);
    gload_lds16(Ag1 + kk, As1);
    gload_lds16(Bg0 + kk, Bs0);
    gload_lds16(Bg1 + kk, Bs1);
    __syncthreads();
    bf16x8 af[4], bv[4];
#pragma unroll
    for (int mi = 0; mi < 4; ++mi)
      af[mi] = *reinterpret_cast<const bf16x8*>(&As[(fra + mi * 16) * 32 + kg]);
#pragma unroll
    for (int ni = 0; ni < 4; ++ni)
      bv[ni] = *reinterpret_cast<const bf16x8*>(&Bs[(frb + ni * 16) * 32 + kg]);
#pragma unroll
    for (int mi = 0; mi < 4; ++mi) {
#pragma unroll
      for (int ni = 0; ni < 4; ++ni)
        acc[mi][ni] =
            __builtin_amdgcn_mfma_f32_16x16x32_bf16(af[mi], bv[ni], acc[mi][ni], 0, 0, 0);
    }
    __syncthreads();
  }

  const int r0 = wr * 64 + ((lane >> 4) << 2);
  const int c0 = wc * 64 + (lane & 15);
#pragma unroll
  for (int mi = 0; mi < 4; ++mi) {
#pragma unroll
    for (int ni = 0; ni < 4; ++ni) {
#pragma unroll
      for (int r = 0; r < 4; ++r) {
        size_t row = (size_t)(bm + r0 + mi * 16 + r);
        size_t col = (size_t)(bn + c0 + ni * 16);
        size_t idx = row * (size_t)N + col;
        float val = acc[mi][ni][r];
        if constexpr (EPI == 0) {
          ((u16*)Cv)[idx] = f2bf(val);
        } else if constexpr (EPI == 2) {  // a = sigmoid(sigmoid(raw))
          float f = 1.f / (1.f + __expf(-val));
          float aa = 1.f / (1.f + __expf(-f));
          ((u16*)Cv)[idx] = f2bf(aa);
        } else {  // EPI == 4: g = silu(acc) * h, in place over h
          float hv = bf2f(((u16*)Cv)[idx]);
          float s = 1.f / (1.f + __expf(-val));
          ((u16*)Cv)[idx] = f2bf(val * s * hv);
        }
      }
    }
  }
}

// ---------------- 256x256 8-phase GEMM (T1+T2+T3+T4+T5) --------------------
// BK=64, 512 thr / 8 waves (2Mx4N), per-wave C = 128x64 (acc[8][4]).
// LDS: 2 dbuf x (A 256x64 + B 256x64) = 128 KiB, XOR-swizzled (col16 ^= row&7)
// via pre-swizzled global source (linear gload_lds dest) + swizzled ds_read.
// EPI: 0 = bf16 store; 3 = f32 store * RS[row]
template <int EPI>
__global__ __launch_bounds__(512, 2) void gemm8(const u16* __restrict__ A,
                                                const u16* __restrict__ BT,
                                                void* __restrict__ Cv,
                                                const float* __restrict__ RS,
                                                int M, int N, int K, int nbx) {
  __shared__ __align__(16) u16 lds_[2][2][256][64];  // [dbuf][A/B][row][col16swz]
  const int tid = threadIdx.x;
  const int lane = tid & 63;
  const int w = tid >> 6;         // 0..7
  const int wr = w >> 2;          // M half
  const int wc = w & 3;           // N quarter

  // bijective XCD swizzle (grid % 8 == 0 by construction)
  const int nwg = gridDim.x;
  const int bid = blockIdx.x;
  const int swz = (bid & 7) * (nwg >> 3) + (bid >> 3);
  const long bm = (long)(swz % nbx) * 256;
  const long bn = (long)(swz / nbx) * 256;

  // staging: wave w owns rows [32w,32w+32) of A-tile and of B-tile; 4 issues
  // of 8 rows each. Linear LDS dest; inverse-swizzled global source:
  // lane l -> LDS (row +l>>3, col16 l&7) must hold elem col16 (l&7)^(l>>3).
  const int sr = lane >> 3;
  const int sc = ((lane & 7) ^ sr) << 3;  // u16
  const u16* Ag = A + (size_t)(bm + w * 32 + sr) * K + sc;
  const u16* Bg = BT + (size_t)(bn + w * 32 + sr) * K + sc;

#define STAGE8(dbuf, t)                                              \
  {                                                                  \
    const u16* ag_ = Ag + (size_t)(t) * 64;                          \
    const u16* bg_ = Bg + (size_t)(t) * 64;                          \
    u16* la_ = &lds_[dbuf][0][w * 32][0];                            \
    u16* lb_ = &lds_[dbuf][1][w * 32][0];                            \
    gload_lds16(ag_, la_);                                           \
    gload_lds16(bg_, lb_);                                           \
    gload_lds16(ag_ + (size_t)8 * K, la_ + 512);                     \
    gload_lds16(bg_ + (size_t)8 * K, lb_ + 512);                     \
    gload_lds16(ag_ + (size_t)16 * K, la_ + 1024);                   \
    gload_lds16(bg_ + (size_t)16 * K, lb_ + 1024);                   \
    gload_lds16(ag_ + (size_t)24 * K, la_ + 1536);                   \
    gload_lds16(bg_ + (size_t)24 * K, lb_ + 1536);                   \
  }

  // ds_read addressing (swizzled): elem col16 e = ks*4 + (lane>>4) read from
  // LDS col16 e ^ (row&7); row&7 == lane&7.
  const int frow = lane & 15;
  const int fk8 = (lane >> 4) << 3;
  const int swz8 = (lane & 7) << 3;
  const int cr0 = fk8 ^ swz8;          // ks=0, u16 col
  const int cr1 = (32 + fk8) ^ swz8;   // ks=1

  f32x4 acc[8][4] = {};

  // prologue: stage tiles 0,1; wait tile 0
  STAGE8(0, 0);
  STAGE8(1, 1);
  asm volatile("s_waitcnt vmcnt(8)" ::: "memory");
  asm volatile("s_barrier" ::: "memory");

  const int NT = K >> 6;
  int cur = 0;
  for (int t = 0; t < NT; ++t) {
    const u16* LA = &lds_[cur][0][0][0];
    const u16* LB = &lds_[cur][1][0][0];
    bf16x8 af[4], bf_[4], ag2[4];
    // ---- ph0: mh0 x ks0
#pragma unroll
    for (int i = 0; i < 4; ++i)
      af[i] = *reinterpret_cast<const bf16x8*>(&LA[(wr * 128 + i * 16 + frow) * 64 + cr0]);
#pragma unroll
    for (int i = 0; i < 4; ++i)
      bf_[i] = *reinterpret_cast<const bf16x8*>(&LB[(wc * 64 + i * 16 + frow) * 64 + cr0]);
    __builtin_amdgcn_s_setprio(1);
#pragma unroll
    for (int i = 0; i < 4; ++i)
#pragma unroll
      for (int j = 0; j < 4; ++j)
        acc[i][j] = __builtin_amdgcn_mfma_f32_16x16x32_bf16(af[i], bf_[j], acc[i][j], 0, 0, 0);
    __builtin_amdgcn_s_setprio(0);
    asm volatile("s_barrier" ::: "memory");
    // ---- ph1: mh1 x ks0 (B reused)
#pragma unroll
    for (int i = 0; i < 4; ++i)
      ag2[i] = *reinterpret_cast<const bf16x8*>(&LA[(wr * 128 + 64 + i * 16 + frow) * 64 + cr0]);
    __builtin_amdgcn_s_setprio(1);
#pragma unroll
    for (int i = 0; i < 4; ++i)
#pragma unroll
      for (int j = 0; j < 4; ++j)
        acc[4 + i][j] = __builtin_amdgcn_mfma_f32_16x16x32_bf16(ag2[i], bf_[j], acc[4 + i][j], 0, 0, 0);
    __builtin_amdgcn_s_setprio(0);
    asm volatile("s_barrier" ::: "memory");
    // ---- ph2: mh0 x ks1
#pragma unroll
    for (int i = 0; i < 4; ++i)
      af[i] = *reinterpret_cast<const bf16x8*>(&LA[(wr * 128 + i * 16 + frow) * 64 + cr1]);
#pragma unroll
    for (int i = 0; i < 4; ++i)
      bf_[i] = *reinterpret_cast<const bf16x8*>(&LB[(wc * 64 + i * 16 + frow) * 64 + cr1]);
    __builtin_amdgcn_s_setprio(1);
#pragma unroll
    for (int i = 0; i < 4; ++i)
#pragma unroll
      for (int j = 0; j < 4; ++j)
        acc[i][j] = __builtin_amdgcn_mfma_f32_16x16x32_bf16(af[i], bf_[j], acc[i][j], 0, 0, 0);
    __builtin_amdgcn_s_setprio(0);
    asm volatile("s_barrier" ::: "memory");
    // ---- ph3: mh1 x ks1
#pragma unroll
    for (int i = 0; i < 4; ++i)
      ag2[i] = *reinterpret_cast<const bf16x8*>(&LA[(wr * 128 + 64 + i * 16 + frow) * 64 + cr1]);
    __builtin_amdgcn_s_setprio(1);
#pragma unroll
    for (int i = 0; i < 4; ++i)
#pragma unroll
      for (int j = 0; j < 4; ++j)
        acc[4 + i][j] = __builtin_amdgcn_mfma_f32_16x16x32_bf16(ag2[i], bf_[j], acc[4 + i][j], 0, 0, 0);
    __builtin_amdgcn_s_setprio(0);
    asm volatile("s_barrier" ::: "memory");  // lds_[cur] fully consumed

    // stage t+2 into freed buffer; counted wait keeps next tile's 8 in flight
    if (t + 2 < NT) {
      STAGE8(cur, t + 2);
      asm volatile("s_waitcnt vmcnt(8)" ::: "memory");
    } else {
      asm volatile("s_waitcnt vmcnt(0)" ::: "memory");
    }
    asm volatile("s_barrier" ::: "memory");
    cur ^= 1;
  }

  // epilogue: C/D col=lane&15, row=(lane>>4)*4+reg
  const int er = (lane >> 4) << 2;
  const int ec = lane & 15;
#pragma unroll
  for (int mf = 0; mf < 8; ++mf) {
#pragma unroll
    for (int r = 0; r < 4; ++r) {
      const size_t row = (size_t)(bm + wr * 128 + mf * 16 + er + r);
      float rscale = 1.f;
      if constexpr (EPI == 3) rscale = RS[row];
#pragma unroll
      for (int nf = 0; nf < 4; ++nf) {
        const size_t col = (size_t)(bn + wc * 64 + nf * 16 + ec);
        const size_t idx = row * (size_t)N + col;
        const float val = acc[mf][nf][r];
        if constexpr (EPI == 0) {
          ((u16*)Cv)[idx] = f2bf(val);
        } else {
          ((float*)Cv)[idx] = val * rscale;
        }
      }
    }
  }
#undef STAGE8
}

// ---------------- chunked gated scan ----------------
__global__ __launch_bounds__(256) void scan_a(const u16* __restrict__ a,
                                              const u16* __restrict__ v,
                                              float* __restrict__ S_p,
                                              float* __restrict__ S_h) {
  const int idx = blockIdx.x * 256 + threadIdx.x;
  const int ch8 = idx & 511;
  const int c = (idx >> 9) & 31;
  const int b = idx >> 14;
  const int ch = ch8 << 3;
  size_t off = ((size_t)(b * 2048 + c * 64)) * 4096 + ch;
  float h[8], p[8];
#pragma unroll
  for (int j = 0; j < 8; ++j) { h[j] = 0.f; p[j] = 1.f; }
  for (int t = 0; t < 64; ++t) {
    u16x8 ua = *(const u16x8*)&a[off];
    u16x8 uv = *(const u16x8*)&v[off];
#pragma unroll
    for (int j = 0; j < 8; ++j) {
      float at = bf2f(ua[j]);
      h[j] = at * h[j] + (1.f - at) * bf2f(uv[j]);
      p[j] *= at;
    }
    off += 4096;
  }
  size_t so = (size_t)(b * 32 + c) * 4096 + ch;
#pragma unroll
  for (int j = 0; j < 8; ++j) { S_p[so + j] = p[j]; S_h[so + j] = h[j]; }
}

__global__ __launch_bounds__(256) void scan_b(const float* __restrict__ S_p,
                                              const float* __restrict__ S_h,
                                              float* __restrict__ Hin) {
  const int idx = blockIdx.x * 256 + threadIdx.x;
  const int b = idx >> 12;
  const int ch = idx & 4095;
  float H = 0.f;
  for (int c = 0; c < 32; ++c) {
    size_t so = (size_t)(b * 32 + c) * 4096 + ch;
    Hin[so] = H;
    H = S_p[so] * H + S_h[so];
  }
}

__global__ __launch_bounds__(256) void scan_c(const u16* __restrict__ a,
                                              u16* __restrict__ vh,
                                              const float* __restrict__ Hin) {
  const int idx = blockIdx.x * 256 + threadIdx.x;
  const int ch8 = idx & 511;
  const int c = (idx >> 9) & 31;
  const int b = idx >> 14;
  const int ch = ch8 << 3;
  size_t so = (size_t)(b * 32 + c) * 4096 + ch;
  float h[8];
#pragma unroll
  for (int j = 0; j < 8; ++j) h[j] = Hin[so + j];
  size_t off = ((size_t)(b * 2048 + c * 64)) * 4096 + ch;
  for (int t = 0; t < 64; ++t) {
    u16x8 ua = *(const u16x8*)&a[off];
    u16x8 uv = *(const u16x8*)&vh[off];
    u16x8 out;
#pragma unroll
    for (int j = 0; j < 8; ++j) {
      float at = bf2f(ua[j]);
      h[j] = at * h[j] + (1.f - at) * bf2f(uv[j]);
      out[j] = f2bf(h[j]);
    }
    *(u16x8*)&vh[off] = out;
    off += 4096;
  }
}

// ---------------- per-row rsqrt(mean(g^2)+eps) -> RS[8192] ----------------
__global__ __launch_bounds__(256) void rowssq(const u16* __restrict__ g,
                                              float* __restrict__ rs) {
  const size_t base = (size_t)blockIdx.x * 4096;
  const int tid = threadIdx.x;
  const int c0 = tid * 16;
  u16 vals[16];
  *(u32x4*)&vals[0] = *(const u32x4*)&g[base + c0];
  *(u32x4*)&vals[8] = *(const u32x4*)&g[base + c0 + 8];
  float s = 0.f;
#pragma unroll
  for (int i = 0; i < 16; ++i) {
    float f = bf2f(vals[i]);
    s += f * f;
  }
#pragma unroll
  for (int o = 32; o > 0; o >>= 1) s += __shfl_down(s, o, 64);
  __shared__ float red[4];
  if ((tid & 63) == 0) red[tid >> 6] = s;
  __syncthreads();
  if (tid == 0) {
    float tot = red[0] + red[1] + red[2] + red[3];
    rs[blockIdx.x] = rsqrtf(tot * (1.0f / 4096.0f) + 1e-6f);
  }
}

extern "C" void kernel_launch(void* const* d_in, const int* in_sizes, int n_in,
                              void* d_out, int out_size, void* d_ws, size_t ws_size,
                              hipStream_t stream) {
  const float* x   = (const float*)d_in[0];
  const float* Wq1 = (const float*)d_in[1];
  const float* Wq2 = (const float*)d_in[2];
  const float* Wk1 = (const float*)d_in[3];
  const float* Wk2 = (const float*)d_in[4];
  const float* Wv  = (const float*)d_in[5];
  const float* Wo  = (const float*)d_in[6];
  const float* nw  = (const float*)d_in[7];

  char* ws = (char*)d_ws;
  // R0 [0,64M): X + WVT, overlaid later by AA (a)
  u16* X     = (u16*)(ws + 0);           // 8192x2048
  u16* WVT   = (u16*)(ws + 33554432);    // 4096x2048
  u16* AA    = (u16*)(ws + 0);           // 8192x4096 overlay
  // R1
  u16* VV    = (u16*)(ws + 67108864);    // 8192x4096 (v -> h -> g in place)
  // R2
  u16* T12   = (u16*)(ws + 134217728);   // 8192x256 (q1 | k1)
  u16* WQK1T = (u16*)(ws + 138412032);   // 256x2048
  u16* WQ2T  = (u16*)(ws + 139460608);   // 4096x128
  u16* WK2T  = (u16*)(ws + 140509184);   // 4096x128
  u16* WOT   = (u16*)(ws + 141557760);   // 2048x4096 (nw folded)
  float* S_P = (float*)(ws + 158334976);
  float* S_H = (float*)(ws + 160432128);
  float* HIN = (float*)(ws + 162529280);
  float* RS  = (float*)(ws + 164626432); // 8192 f32; end ~157 MB

  cast_kernel<<<16384, 256, 0, stream>>>(x, X, 16777216L);
  transpose_cast<<<dim3(4, 64),   dim3(32, 8), 0, stream>>>(Wq1, WQK1T, 2048, 128);
  transpose_cast<<<dim3(4, 64),   dim3(32, 8), 0, stream>>>(Wk1, WQK1T + 128 * 2048, 2048, 128);
  transpose_cast<<<dim3(128, 4),  dim3(32, 8), 0, stream>>>(Wq2, WQ2T, 128, 4096);
  transpose_cast<<<dim3(128, 4),  dim3(32, 8), 0, stream>>>(Wk2, WK2T, 128, 4096);
  transpose_cast<<<dim3(128, 64), dim3(32, 8), 0, stream>>>(Wv, WVT, 2048, 4096);
  transpose_cast_nw<<<dim3(64, 128), dim3(32, 8), 0, stream>>>(Wo, nw, WOT, 4096, 2048);

  // q1|k1 fused: T12 = X @ [Wq1 Wk1]
  gemm_bt<0><<<dim3(64, 2), 256, 0, stream>>>(X, 2048, WQK1T, T12, 8192, 256, 2048);
  // v = X @ Wv  (8-phase 256^2)
  gemm8<0><<<512, 512, 0, stream>>>(X, WVT, VV, nullptr, 8192, 4096, 2048, 32);
  // a = sig(sig(k1 @ Wk2)) into R0 overlay (X/WVT dead)
  gemm_bt<2><<<dim3(64, 32), 256, 0, stream>>>(T12 + 128, 256, WK2T, AA, 8192, 4096, 128);

  // chunked scan: VV := h (in place)
  scan_a<<<256, 256, 0, stream>>>(AA, VV, S_P, S_H);
  scan_b<<<64, 256, 0, stream>>>(S_P, S_H, HIN);
  scan_c<<<256, 256, 0, stream>>>(AA, VV, HIN);

  // g = silu(q1 @ Wq2) * h, in place over VV
  gemm_bt<4><<<dim3(64, 32), 256, 0, stream>>>(T12, 256, WQ2T, VV, 8192, 4096, 128);

  // row scales; then out = (g * RS[row]) @ (Wo*nw)
  rowssq<<<8192, 256, 0, stream>>>(VV, RS);
  gemm8<3><<<256, 512, 0, stream>>>(VV, WOT, d_out, RS, 8192, 2048, 4096, 32);
}

// Round 7
// 665.756 us; speedup vs baseline: 1.2644x; 1.0128x over previous
//
#include <hip/hip_runtime.h>

// Hgru1: q=silu((x@Wq1)@Wq2); a=sig(sig((x@Wk1)@Wk2)); v=x@Wv;
// h_t = a_t h_{t-1} + (1-a_t) v_t ; out = RMSNorm(q*h)*nw @ Wo
// B=4 N=2048 E=2048 HD=128 E2=4096, M=B*N=8192

typedef unsigned short u16;
typedef __attribute__((ext_vector_type(4))) float f32x4;
typedef __attribute__((ext_vector_type(8))) __bf16 bf16x8;
typedef __attribute__((ext_vector_type(8))) u16 u16x8;
typedef __attribute__((ext_vector_type(4))) unsigned int u32x4;

__device__ __forceinline__ float bf2f(u16 u) {
  unsigned int i = ((unsigned int)u) << 16;
  return __builtin_bit_cast(float, i);
}
__device__ __forceinline__ u16 f2bf(float f) {
  unsigned int i = __builtin_bit_cast(unsigned int, f);
  i += 0x7fffu + ((i >> 16) & 1u);   // RNE
  return (u16)(i >> 16);
}

__device__ __forceinline__ void gload_lds16(const u16* g, u16* l) {
  __builtin_amdgcn_global_load_lds(
      (const __attribute__((address_space(1))) void*)g,
      (__attribute__((address_space(3))) void*)l, 16, 0, 0);
}

// ---------------- casts ----------------
__global__ __launch_bounds__(256) void cast_kernel(const float* __restrict__ in,
                                                   u16* __restrict__ out, long n) {
  long i = ((long)blockIdx.x * 256 + threadIdx.x) * 4;
  if (i >= n) return;
  f32x4 fv = *(const f32x4*)&in[i];
  unsigned long long pk = (unsigned long long)f2bf(fv[0]) |
                          ((unsigned long long)f2bf(fv[1]) << 16) |
                          ((unsigned long long)f2bf(fv[2]) << 32) |
                          ((unsigned long long)f2bf(fv[3]) << 48);
  *(unsigned long long*)&out[i] = pk;
}

// W [R][Cc] f32 -> WT [Cc][R] bf16   (grid: (Cc/32, R/32), block (32,8))
__global__ __launch_bounds__(256) void transpose_cast(const float* __restrict__ W,
                                                      u16* __restrict__ WT, int R, int Cc) {
  __shared__ float tile[32][33];
  const int tx = threadIdx.x, ty = threadIdx.y;
  const int x = blockIdx.x * 32 + tx;
  const int ybase = blockIdx.y * 32;
#pragma unroll
  for (int i = 0; i < 32; i += 8)
    tile[ty + i][tx] = W[(size_t)(ybase + ty + i) * Cc + x];
  __syncthreads();
  const int xt = ybase + tx;
  const int ytbase = blockIdx.x * 32;
#pragma unroll
  for (int i = 0; i < 32; i += 8)
    WT[(size_t)(ytbase + ty + i) * R + xt] = f2bf(tile[tx][ty + i]);
}

// Wo variant: WT[n][k] = Wo[k][n] * nw[k]  (folds RMSNorm weight into Wo)
__global__ __launch_bounds__(256) void transpose_cast_nw(const float* __restrict__ W,
                                                         const float* __restrict__ nw,
                                                         u16* __restrict__ WT, int R, int Cc) {
  __shared__ float tile[32][33];
  const int tx = threadIdx.x, ty = threadIdx.y;
  const int x = blockIdx.x * 32 + tx;
  const int ybase = blockIdx.y * 32;
#pragma unroll
  for (int i = 0; i < 32; i += 8)
    tile[ty + i][tx] = W[(size_t)(ybase + ty + i) * Cc + x];
  __syncthreads();
  const int xt = ybase + tx;           // k index
  const float s = nw[xt];
  const int ytbase = blockIdx.x * 32;
#pragma unroll
  for (int i = 0; i < 32; i += 8)
    WT[(size_t)(ytbase + ty + i) * R + xt] = f2bf(tile[tx][ty + i] * s);
}

// ---------------- 128x128 GEMM (2-barrier, for K=128/N=256 cases) ----------
// C[m][n] = sum_k A[m][k]*BT[n][k]; A row stride = lda.
// EPI: 0 bf16 store; 2 sig(sig)->bf16; 4 in-place g = silu(acc)*h
template <int EPI>
__global__ __launch_bounds__(256) void gemm_bt(const u16* __restrict__ A, int lda,
                                               const u16* __restrict__ BT,
                                               void* __restrict__ Cv,
                                               int M, int N, int K) {
  __shared__ __align__(16) u16 As[4096];
  __shared__ __align__(16) u16 Bs[4096];
  const int tid = threadIdx.x;
  const int lane = tid & 63;
  const int wid = tid >> 6;
  const int wr = wid >> 1, wc = wid & 1;
  const long bm = (long)blockIdx.x * 128;
  const long bn = (long)blockIdx.y * 128;

  const int sm = lane >> 2;
  const int sk = (lane & 3) << 3;
  const u16* Ag0 = A + (size_t)(bm + wid * 16 + sm) * lda + sk;
  const u16* Ag1 = A + (size_t)(bm + 64 + wid * 16 + sm) * lda + sk;
  const u16* Bg0 = BT + (size_t)(bn + wid * 16 + sm) * K + sk;
  const u16* Bg1 = BT + (size_t)(bn + 64 + wid * 16 + sm) * K + sk;
  u16* As0 = As + wid * 512;
  u16* As1 = As + 2048 + wid * 512;
  u16* Bs0 = Bs + wid * 512;
  u16* Bs1 = Bs + 2048 + wid * 512;

  f32x4 acc[4][4] = {};

  const int fra = wr * 64 + (lane & 15);
  const int frb = wc * 64 + (lane & 15);
  const int kg = (lane >> 4) << 3;

  for (int kk = 0; kk < K; kk += 32) {
    gload_lds16(Ag0 + kk, As0);
    gload_lds16(Ag1 + kk, As1);
    gload_lds16(Bg0 + kk, Bs0);
    gload_lds16(Bg1 + kk, Bs1);
    __syncthreads();
    bf16x8 af[4], bv[4];
#pragma unroll
    for (int mi = 0; mi < 4; ++mi)
      af[mi] = *reinterpret_cast<const bf16x8*>(&As[(fra + mi * 16) * 32 + kg]);
#pragma unroll
    for (int ni = 0; ni < 4; ++ni)
      bv[ni] = *reinterpret_cast<const bf16x8*>(&Bs[(frb + ni * 16) * 32 + kg]);
#pragma unroll
    for (int mi = 0; mi < 4; ++mi) {
#pragma unroll
      for (int ni = 0; ni < 4; ++ni)
        acc[mi][ni] =
            __builtin_amdgcn_mfma_f32_16x16x32_bf16(af[mi], bv[ni], acc[mi][ni], 0, 0, 0);
    }
    __syncthreads();
  }

  const int r0 = wr * 64 + ((lane >> 4) << 2);
  const int c0 = wc * 64 + (lane & 15);
#pragma unroll
  for (int mi = 0; mi < 4; ++mi) {
#pragma unroll
    for (int ni = 0; ni < 4; ++ni) {
#pragma unroll
      for (int r = 0; r < 4; ++r) {
        size_t row = (size_t)(bm + r0 + mi * 16 + r);
        size_t col = (size_t)(bn + c0 + ni * 16);
        size_t idx = row * (size_t)N + col;
        float val = acc[mi][ni][r];
        if constexpr (EPI == 0) {
          ((u16*)Cv)[idx] = f2bf(val);
        } else if constexpr (EPI == 2) {  // a = sigmoid(sigmoid(raw))
          float f = 1.f / (1.f + __expf(-val));
          float aa = 1.f / (1.f + __expf(-f));
          ((u16*)Cv)[idx] = f2bf(aa);
        } else {  // EPI == 4: g = silu(acc) * h, in place over h
          float hv = bf2f(((u16*)Cv)[idx]);
          float s = 1.f / (1.f + __expf(-val));
          ((u16*)Cv)[idx] = f2bf(val * s * hv);
        }
      }
    }
  }
}

// ---------------- 256x256 GEMM, m201-isomorphic schedule -------------------
// BK=32, 4 LDS buffers [4][2][256][32] (128 KiB), 2 phases/tile, 8 waves
// (2Mx4N), per-wave C = 128x64 (acc[8][4]).  Tile u stages tile u+3 into
// buffer (u+3)&3 (fully dead) -> uniform 2 gloads/phase, race-free.
// vmcnt(8) at tile top (= tiles u+1,u+2 staging in flight, never 0).
// Swizzle: slot' = slot ^ ((row>>1)&3) on 16B slots (64B rows, 2-way alias =
// free), applied as inverse-swizzled global source + swizzled ds_read.
// EPI: 0 = bf16 store; 3 = f32 store * RS[row]
template <int EPI>
__global__ __launch_bounds__(512, 2) void gemm8(const u16* __restrict__ A,
                                                const u16* __restrict__ BT,
                                                void* __restrict__ Cv,
                                                const float* __restrict__ RS,
                                                int M, int N, int K, int nby) {
  __shared__ __align__(16) u16 lds_[4][2][256][32];  // [buf][A/B][row][col]
  const int tid = threadIdx.x;
  const int lane = tid & 63;
  const int w = tid >> 6;         // 0..7
  const int wr = w >> 2;          // M half
  const int wc = w & 3;           // N quarter

  // bijective XCD swizzle; M-stripes per XCD (A-chunk fits 4MiB L2)
  const int nwg = gridDim.x;
  const int bid = blockIdx.x;
  const int swz = (bid & 7) * (nwg >> 3) + (bid >> 3);
  const long bm = (long)(swz / nby) * 256;
  const long bn = (long)(swz % nby) * 256;

  // staging: wave w owns rows [32w,32w+32); 2 gloads (16 rows each) per
  // matrix per tile. Linear LDS dest; inverse-swizzled global source:
  // lane l -> row l>>2, phys slot l&3 holds logical slot (l&3)^((l>>3)&3).
  const int srow = lane >> 2;
  const int scol = ((lane & 3) ^ ((lane >> 3) & 3)) << 3;  // u16
  const u16* Ag = A + (size_t)(bm + w * 32 + srow) * K + scol;
  const u16* Bg = BT + (size_t)(bn + w * 32 + srow) * K + scol;

#define STG_A(t)                                                     \
  {                                                                  \
    const u16* s_ = Ag + (size_t)(t) * 32;                           \
    u16* d_ = &lds_[(t) & 3][0][w * 32][0];                          \
    gload_lds16(s_, d_);                                             \
    gload_lds16(s_ + (size_t)16 * K, d_ + 512);                      \
  }
#define STG_B(t)                                                     \
  {                                                                  \
    const u16* s_ = Bg + (size_t)(t) * 32;                           \
    u16* d_ = &lds_[(t) & 3][1][w * 32][0];                          \
    gload_lds16(s_, d_);                                             \
    gload_lds16(s_ + (size_t)16 * K, d_ + 512);                      \
  }

  // ds_read: logical k-slot = lane>>4, row = base + frow;
  // physical slot = (lane>>4) ^ ((frow>>1)&3)
  const int frow = lane & 15;
  const int colw = (((lane >> 4) ^ ((frow >> 1) & 3)) << 3);  // u16

  f32x4 acc[8][4] = {};

  const int NT = K >> 5;
  // prologue: stage tiles 0,1,2 (12 gloads/wave)
  STG_A(0); STG_B(0);
  STG_A(1); STG_B(1);
  STG_A(2); STG_B(2);

  for (int u = 0; u < NT; ++u) {
    const u16* LA = &lds_[u & 3][0][0][0];
    const u16* LB = &lds_[u & 3][1][0][0];
    // tile gate: newest 8 outstanding = tiles u+1,u+2 staging; tile u landed
    asm volatile("s_waitcnt vmcnt(8)" ::: "memory");
    __builtin_amdgcn_s_barrier();
    bf16x8 a0[4], b0[4], a1[4];
    // ---- ph0 (rows wr*128 .. +64)
#pragma unroll
    for (int i = 0; i < 4; ++i)
      a0[i] = *reinterpret_cast<const bf16x8*>(&LA[(wr * 128 + i * 16 + frow) * 32 + colw]);
#pragma unroll
    for (int i = 0; i < 4; ++i)
      b0[i] = *reinterpret_cast<const bf16x8*>(&LB[(wc * 64 + i * 16 + frow) * 32 + colw]);
    if (u + 3 < NT) STG_A(u + 3);
    __builtin_amdgcn_s_barrier();
    asm volatile("s_waitcnt lgkmcnt(0)" ::: "memory");
    __builtin_amdgcn_s_setprio(1);
#pragma unroll
    for (int i = 0; i < 4; ++i)
#pragma unroll
      for (int j = 0; j < 4; ++j)
        acc[i][j] = __builtin_amdgcn_mfma_f32_16x16x32_bf16(a0[i], b0[j], acc[i][j], 0, 0, 0);
    __builtin_amdgcn_s_setprio(0);
    __builtin_amdgcn_s_barrier();
    // ---- ph1 (rows wr*128+64 .. +128; B regs reused)
#pragma unroll
    for (int i = 0; i < 4; ++i)
      a1[i] = *reinterpret_cast<const bf16x8*>(&LA[(wr * 128 + 64 + i * 16 + frow) * 32 + colw]);
    if (u + 3 < NT) STG_B(u + 3);
    __builtin_amdgcn_s_barrier();
    asm volatile("s_waitcnt lgkmcnt(0)" ::: "memory");
    __builtin_amdgcn_s_setprio(1);
#pragma unroll
    for (int i = 0; i < 4; ++i)
#pragma unroll
      for (int j = 0; j < 4; ++j)
        acc[4 + i][j] = __builtin_amdgcn_mfma_f32_16x16x32_bf16(a1[i], b0[j], acc[4 + i][j], 0, 0, 0);
    __builtin_amdgcn_s_setprio(0);
    __builtin_amdgcn_s_barrier();
  }

  // epilogue: C/D col=lane&15, row=(lane>>4)*4+reg
  const int er = (lane >> 4) << 2;
  const int ec = lane & 15;
#pragma unroll
  for (int mf = 0; mf < 8; ++mf) {
#pragma unroll
    for (int r = 0; r < 4; ++r) {
      const size_t row = (size_t)(bm + wr * 128 + mf * 16 + er + r);
      float rscale = 1.f;
      if constexpr (EPI == 3) rscale = RS[row];
#pragma unroll
      for (int nf = 0; nf < 4; ++nf) {
        const size_t col = (size_t)(bn + wc * 64 + nf * 16 + ec);
        const size_t idx = row * (size_t)N + col;
        const float val = acc[mf][nf][r];
        if constexpr (EPI == 0) {
          ((u16*)Cv)[idx] = f2bf(val);
        } else {
          ((float*)Cv)[idx] = val * rscale;
        }
      }
    }
  }
#undef STG_A
#undef STG_B
}

// ---------------- chunked gated scan ----------------
__global__ __launch_bounds__(256) void scan_a(const u16* __restrict__ a,
                                              const u16* __restrict__ v,
                                              float* __restrict__ S_p,
                                              float* __restrict__ S_h) {
  const int idx = blockIdx.x * 256 + threadIdx.x;
  const int ch8 = idx & 511;
  const int c = (idx >> 9) & 31;
  const int b = idx >> 14;
  const int ch = ch8 << 3;
  size_t off = ((size_t)(b * 2048 + c * 64)) * 4096 + ch;
  float h[8], p[8];
#pragma unroll
  for (int j = 0; j < 8; ++j) { h[j] = 0.f; p[j] = 1.f; }
  for (int t = 0; t < 64; ++t) {
    u16x8 ua = *(const u16x8*)&a[off];
    u16x8 uv = *(const u16x8*)&v[off];
#pragma unroll
    for (int j = 0; j < 8; ++j) {
      float at = bf2f(ua[j]);
      h[j] = at * h[j] + (1.f - at) * bf2f(uv[j]);
      p[j] *= at;
    }
    off += 4096;
  }
  size_t so = (size_t)(b * 32 + c) * 4096 + ch;
#pragma unroll
  for (int j = 0; j < 8; ++j) { S_p[so + j] = p[j]; S_h[so + j] = h[j]; }
}

__global__ __launch_bounds__(256) void scan_b(const float* __restrict__ S_p,
                                              const float* __restrict__ S_h,
                                              float* __restrict__ Hin) {
  const int idx = blockIdx.x * 256 + threadIdx.x;
  const int b = idx >> 12;
  const int ch = idx & 4095;
  float H = 0.f;
  for (int c = 0; c < 32; ++c) {
    size_t so = (size_t)(b * 32 + c) * 4096 + ch;
    Hin[so] = H;
    H = S_p[so] * H + S_h[so];
  }
}

__global__ __launch_bounds__(256) void scan_c(const u16* __restrict__ a,
                                              u16* __restrict__ vh,
                                              const float* __restrict__ Hin) {
  const int idx = blockIdx.x * 256 + threadIdx.x;
  const int ch8 = idx & 511;
  const int c = (idx >> 9) & 31;
  const int b = idx >> 14;
  const int ch = ch8 << 3;
  size_t so = (size_t)(b * 32 + c) * 4096 + ch;
  float h[8];
#pragma unroll
  for (int j = 0; j < 8; ++j) h[j] = Hin[so + j];
  size_t off = ((size_t)(b * 2048 + c * 64)) * 4096 + ch;
  for (int t = 0; t < 64; ++t) {
    u16x8 ua = *(const u16x8*)&a[off];
    u16x8 uv = *(const u16x8*)&vh[off];
    u16x8 out;
#pragma unroll
    for (int j = 0; j < 8; ++j) {
      float at = bf2f(ua[j]);
      h[j] = at * h[j] + (1.f - at) * bf2f(uv[j]);
      out[j] = f2bf(h[j]);
    }
    *(u16x8*)&vh[off] = out;
    off += 4096;
  }
}

// ---------------- per-row rsqrt(mean(g^2)+eps) -> RS[8192] ----------------
__global__ __launch_bounds__(256) void rowssq(const u16* __restrict__ g,
                                              float* __restrict__ rs) {
  const size_t base = (size_t)blockIdx.x * 4096;
  const int tid = threadIdx.x;
  const int c0 = tid * 16;
  u16 vals[16];
  *(u32x4*)&vals[0] = *(const u32x4*)&g[base + c0];
  *(u32x4*)&vals[8] = *(const u32x4*)&g[base + c0 + 8];
  float s = 0.f;
#pragma unroll
  for (int i = 0; i < 16; ++i) {
    float f = bf2f(vals[i]);
    s += f * f;
  }
#pragma unroll
  for (int o = 32; o > 0; o >>= 1) s += __shfl_down(s, o, 64);
  __shared__ float red[4];
  if ((tid & 63) == 0) red[tid >> 6] = s;
  __syncthreads();
  if (tid == 0) {
    float tot = red[0] + red[1] + red[2] + red[3];
    rs[blockIdx.x] = rsqrtf(tot * (1.0f / 4096.0f) + 1e-6f);
  }
}

extern "C" void kernel_launch(void* const* d_in, const int* in_sizes, int n_in,
                              void* d_out, int out_size, void* d_ws, size_t ws_size,
                              hipStream_t stream) {
  const float* x   = (const float*)d_in[0];
  const float* Wq1 = (const float*)d_in[1];
  const float* Wq2 = (const float*)d_in[2];
  const float* Wk1 = (const float*)d_in[3];
  const float* Wk2 = (const float*)d_in[4];
  const float* Wv  = (const float*)d_in[5];
  const float* Wo  = (const float*)d_in[6];
  const float* nw  = (const float*)d_in[7];

  char* ws = (char*)d_ws;
  // R0 [0,64M): X + WVT, overlaid later by AA (a)
  u16* X     = (u16*)(ws + 0);           // 8192x2048
  u16* WVT   = (u16*)(ws + 33554432);    // 4096x2048
  u16* AA    = (u16*)(ws + 0);           // 8192x4096 overlay
  // R1
  u16* VV    = (u16*)(ws + 67108864);    // 8192x4096 (v -> h -> g in place)
  // R2
  u16* T12   = (u16*)(ws + 134217728);   // 8192x256 (q1 | k1)
  u16* WQK1T = (u16*)(ws + 138412032);   // 256x2048
  u16* WQ2T  = (u16*)(ws + 139460608);   // 4096x128
  u16* WK2T  = (u16*)(ws + 140509184);   // 4096x128
  u16* WOT   = (u16*)(ws + 141557760);   // 2048x4096 (nw folded)
  float* S_P = (float*)(ws + 158334976);
  float* S_H = (float*)(ws + 160432128);
  float* HIN = (float*)(ws + 162529280);
  float* RS  = (float*)(ws + 164626432); // 8192 f32; end ~157 MB

  cast_kernel<<<16384, 256, 0, stream>>>(x, X, 16777216L);
  transpose_cast<<<dim3(4, 64),   dim3(32, 8), 0, stream>>>(Wq1, WQK1T, 2048, 128);
  transpose_cast<<<dim3(4, 64),   dim3(32, 8), 0, stream>>>(Wk1, WQK1T + 128 * 2048, 2048, 128);
  transpose_cast<<<dim3(128, 4),  dim3(32, 8), 0, stream>>>(Wq2, WQ2T, 128, 4096);
  transpose_cast<<<dim3(128, 4),  dim3(32, 8), 0, stream>>>(Wk2, WK2T, 128, 4096);
  transpose_cast<<<dim3(128, 64), dim3(32, 8), 0, stream>>>(Wv, WVT, 2048, 4096);
  transpose_cast_nw<<<dim3(64, 128), dim3(32, 8), 0, stream>>>(Wo, nw, WOT, 4096, 2048);

  // q1|k1 fused: T12 = X @ [Wq1 Wk1]
  gemm_bt<0><<<dim3(64, 2), 256, 0, stream>>>(X, 2048, WQK1T, T12, 8192, 256, 2048);
  // v = X @ Wv  (256^2 4-buffer pipelined; nby = N/256 = 16)
  gemm8<0><<<512, 512, 0, stream>>>(X, WVT, VV, nullptr, 8192, 4096, 2048, 16);
  // a = sig(sig(k1 @ Wk2)) into R0 overlay (X/WVT dead)
  gemm_bt<2><<<dim3(64, 32), 256, 0, stream>>>(T12 + 128, 256, WK2T, AA, 8192, 4096, 128);

  // chunked scan: VV := h (in place)
  scan_a<<<256, 256, 0, stream>>>(AA, VV, S_P, S_H);
  scan_b<<<64, 256, 0, stream>>>(S_P, S_H, HIN);
  scan_c<<<256, 256, 0, stream>>>(AA, VV, HIN);

  // g = silu(q1 @ Wq2) * h, in place over VV
  gemm_bt<4><<<dim3(64, 32), 256, 0, stream>>>(T12, 256, WQ2T, VV, 8192, 4096, 128);

  // row scales; then out = (g * RS[row]) @ (Wo*nw)   (nby = 2048/256 = 8)
  rowssq<<<8192, 256, 0, stream>>>(VV, RS);
  gemm8<3><<<256, 512, 0, stream>>>(VV, WOT, d_out, RS, 8192, 2048, 4096, 8);
}

// Round 8
// 659.340 us; speedup vs baseline: 1.2767x; 1.0097x over previous
//
#include <hip/hip_runtime.h>

// Hgru1: q=silu((x@Wq1)@Wq2); a=sig(sig((x@Wk1)@Wk2)); v=x@Wv;
// h_t = a_t h_{t-1} + (1-a_t) v_t ; out = RMSNorm(q*h)*nw @ Wo
// B=4 N=2048 E=2048 HD=128 E2=4096, M=B*N=8192

typedef unsigned short u16;
typedef __attribute__((ext_vector_type(4))) float f32x4;
typedef __attribute__((ext_vector_type(8))) __bf16 bf16x8;
typedef __attribute__((ext_vector_type(8))) u16 u16x8;
typedef __attribute__((ext_vector_type(4))) unsigned int u32x4;

__device__ __forceinline__ float bf2f(u16 u) {
  unsigned int i = ((unsigned int)u) << 16;
  return __builtin_bit_cast(float, i);
}
__device__ __forceinline__ u16 f2bf(float f) {
  unsigned int i = __builtin_bit_cast(unsigned int, f);
  i += 0x7fffu + ((i >> 16) & 1u);   // RNE
  return (u16)(i >> 16);
}

__device__ __forceinline__ void gload_lds16(const u16* g, u16* l) {
  __builtin_amdgcn_global_load_lds(
      (const __attribute__((address_space(1))) void*)g,
      (__attribute__((address_space(3))) void*)l, 16, 0, 0);
}

// ---------------- casts ----------------
__global__ __launch_bounds__(256) void cast_kernel(const float* __restrict__ in,
                                                   u16* __restrict__ out, long n) {
  long i = ((long)blockIdx.x * 256 + threadIdx.x) * 4;
  if (i >= n) return;
  f32x4 fv = *(const f32x4*)&in[i];
  unsigned long long pk = (unsigned long long)f2bf(fv[0]) |
                          ((unsigned long long)f2bf(fv[1]) << 16) |
                          ((unsigned long long)f2bf(fv[2]) << 32) |
                          ((unsigned long long)f2bf(fv[3]) << 48);
  *(unsigned long long*)&out[i] = pk;
}

// W [R][Cc] f32 -> WT [Cc][R] bf16   (grid: (Cc/32, R/32), block (32,8))
__global__ __launch_bounds__(256) void transpose_cast(const float* __restrict__ W,
                                                      u16* __restrict__ WT, int R, int Cc) {
  __shared__ float tile[32][33];
  const int tx = threadIdx.x, ty = threadIdx.y;
  const int x = blockIdx.x * 32 + tx;
  const int ybase = blockIdx.y * 32;
#pragma unroll
  for (int i = 0; i < 32; i += 8)
    tile[ty + i][tx] = W[(size_t)(ybase + ty + i) * Cc + x];
  __syncthreads();
  const int xt = ybase + tx;
  const int ytbase = blockIdx.x * 32;
#pragma unroll
  for (int i = 0; i < 32; i += 8)
    WT[(size_t)(ytbase + ty + i) * R + xt] = f2bf(tile[tx][ty + i]);
}

// Wo variant: WT[n][k] = Wo[k][n] * nw[k]  (folds RMSNorm weight into Wo)
__global__ __launch_bounds__(256) void transpose_cast_nw(const float* __restrict__ W,
                                                         const float* __restrict__ nw,
                                                         u16* __restrict__ WT, int R, int Cc) {
  __shared__ float tile[32][33];
  const int tx = threadIdx.x, ty = threadIdx.y;
  const int x = blockIdx.x * 32 + tx;
  const int ybase = blockIdx.y * 32;
#pragma unroll
  for (int i = 0; i < 32; i += 8)
    tile[ty + i][tx] = W[(size_t)(ybase + ty + i) * Cc + x];
  __syncthreads();
  const int xt = ybase + tx;           // k index
  const float s = nw[xt];
  const int ytbase = blockIdx.x * 32;
#pragma unroll
  for (int i = 0; i < 32; i += 8)
    WT[(size_t)(ytbase + ty + i) * R + xt] = f2bf(tile[tx][ty + i] * s);
}

// ---------------- 128x128 GEMM (2-barrier, for K=128/N=256 cases) ----------
// C[m][n] = sum_k A[m][k]*BT[n][k]; A row stride = lda.
// EPI: 0 bf16 store; 2 sig(sig)->bf16; 4 in-place g = silu(acc)*h
template <int EPI>
__global__ __launch_bounds__(256) void gemm_bt(const u16* __restrict__ A, int lda,
                                               const u16* __restrict__ BT,
                                               void* __restrict__ Cv,
                                               int M, int N, int K) {
  __shared__ __align__(16) u16 As[4096];
  __shared__ __align__(16) u16 Bs[4096];
  const int tid = threadIdx.x;
  const int lane = tid & 63;
  const int wid = tid >> 6;
  const int wr = wid >> 1, wc = wid & 1;
  const long bm = (long)blockIdx.x * 128;
  const long bn = (long)blockIdx.y * 128;

  const int sm = lane >> 2;
  const int sk = (lane & 3) << 3;
  const u16* Ag0 = A + (size_t)(bm + wid * 16 + sm) * lda + sk;
  const u16* Ag1 = A + (size_t)(bm + 64 + wid * 16 + sm) * lda + sk;
  const u16* Bg0 = BT + (size_t)(bn + wid * 16 + sm) * K + sk;
  const u16* Bg1 = BT + (size_t)(bn + 64 + wid * 16 + sm) * K + sk;
  u16* As0 = As + wid * 512;
  u16* As1 = As + 2048 + wid * 512;
  u16* Bs0 = Bs + wid * 512;
  u16* Bs1 = Bs + 2048 + wid * 512;

  f32x4 acc[4][4] = {};

  const int fra = wr * 64 + (lane & 15);
  const int frb = wc * 64 + (lane & 15);
  const int kg = (lane >> 4) << 3;

  for (int kk = 0; kk < K; kk += 32) {
    gload_lds16(Ag0 + kk, As0);
    gload_lds16(Ag1 + kk, As1);
    gload_lds16(Bg0 + kk, Bs0);
    gload_lds16(Bg1 + kk, Bs1);
    __syncthreads();
    bf16x8 af[4], bv[4];
#pragma unroll
    for (int mi = 0; mi < 4; ++mi)
      af[mi] = *reinterpret_cast<const bf16x8*>(&As[(fra + mi * 16) * 32 + kg]);
#pragma unroll
    for (int ni = 0; ni < 4; ++ni)
      bv[ni] = *reinterpret_cast<const bf16x8*>(&Bs[(frb + ni * 16) * 32 + kg]);
#pragma unroll
    for (int mi = 0; mi < 4; ++mi) {
#pragma unroll
      for (int ni = 0; ni < 4; ++ni)
        acc[mi][ni] =
            __builtin_amdgcn_mfma_f32_16x16x32_bf16(af[mi], bv[ni], acc[mi][ni], 0, 0, 0);
    }
    __syncthreads();
  }

  const int r0 = wr * 64 + ((lane >> 4) << 2);
  const int c0 = wc * 64 + (lane & 15);
#pragma unroll
  for (int mi = 0; mi < 4; ++mi) {
#pragma unroll
    for (int ni = 0; ni < 4; ++ni) {
#pragma unroll
      for (int r = 0; r < 4; ++r) {
        size_t row = (size_t)(bm + r0 + mi * 16 + r);
        size_t col = (size_t)(bn + c0 + ni * 16);
        size_t idx = row * (size_t)N + col;
        float val = acc[mi][ni][r];
        if constexpr (EPI == 0) {
          ((u16*)Cv)[idx] = f2bf(val);
        } else if constexpr (EPI == 2) {  // a = sigmoid(sigmoid(raw))
          float f = 1.f / (1.f + __expf(-val));
          float aa = 1.f / (1.f + __expf(-f));
          ((u16*)Cv)[idx] = f2bf(aa);
        } else {  // EPI == 4: g = silu(acc) * h, in place over h
          float hv = bf2f(((u16*)Cv)[idx]);
          float s = 1.f / (1.f + __expf(-val));
          ((u16*)Cv)[idx] = f2bf(val * s * hv);
        }
      }
    }
  }
}

// ---------------- 256x256 GEMM, barrier-minimal pipelined schedule ---------
// BK=32, 4 LDS buffers [4][2][256][32] (128 KiB), 8 waves (2Mx4N), per-wave
// C = 128x64 (acc[8][4]).  ONE barrier per K-tile: {counted vmcnt -> s_barrier
// -> stage tile u+3 -> ds_reads + 2x16 MFMA with compiler-counted lgkmcnt}.
// Buffer (u+3)&3 == (u-1)&3 is dead once all waves pass the top barrier
// (every wave's tile-(u-1) ds_reads are waitcnt-complete before it reaches a
// barrier), so staging after the barrier is race-free. Waves drift within the
// tile -> LDS reads of one wave overlap MFMAs of another (T5 setprio pays).
// Tail vmcnt counted exactly: 8 (u<=NT-3), 4 (u==NT-2), 0 (u==NT-1).
// Swizzle: 16B slot' = slot ^ ((row>>1)&3), inverse-swizzled global source +
// swizzled ds_read (bank-conflict-free, verified r7: SQ_LDS_BANK_CONFLICT=0).
// EPI: 0 = bf16 store; 3 = f32 store * RS[row]
template <int EPI>
__global__ __launch_bounds__(512, 2) void gemm8(const u16* __restrict__ A,
                                                const u16* __restrict__ BT,
                                                void* __restrict__ Cv,
                                                const float* __restrict__ RS,
                                                int M, int N, int K, int nby) {
  __shared__ __align__(16) u16 lds_[4][2][256][32];  // [buf][A/B][row][col]
  const int tid = threadIdx.x;
  const int lane = tid & 63;
  const int w = tid >> 6;         // 0..7
  const int wr = w >> 2;          // M half
  const int wc = w & 3;           // N quarter

  // bijective XCD swizzle; M-stripes per XCD (A-chunk fits 4MiB L2)
  const int nwg = gridDim.x;
  const int bid = blockIdx.x;
  const int swz = (bid & 7) * (nwg >> 3) + (bid >> 3);
  const long bm = (long)(swz / nby) * 256;
  const long bn = (long)(swz % nby) * 256;

  // staging: wave w owns rows [32w,32w+32); 2 gloads (16 rows each) per
  // matrix per tile. Linear LDS dest; inverse-swizzled global source:
  // lane l -> row l>>2, phys slot l&3 holds logical slot (l&3)^((l>>3)&3).
  const int srow = lane >> 2;
  const int scol = ((lane & 3) ^ ((lane >> 3) & 3)) << 3;  // u16
  const u16* Ag = A + (size_t)(bm + w * 32 + srow) * K + scol;
  const u16* Bg = BT + (size_t)(bn + w * 32 + srow) * K + scol;

#define STG_A(t)                                                     \
  {                                                                  \
    const u16* s_ = Ag + (size_t)(t) * 32;                           \
    u16* d_ = &lds_[(t) & 3][0][w * 32][0];                          \
    gload_lds16(s_, d_);                                             \
    gload_lds16(s_ + (size_t)16 * K, d_ + 512);                      \
  }
#define STG_B(t)                                                     \
  {                                                                  \
    const u16* s_ = Bg + (size_t)(t) * 32;                           \
    u16* d_ = &lds_[(t) & 3][1][w * 32][0];                          \
    gload_lds16(s_, d_);                                             \
    gload_lds16(s_ + (size_t)16 * K, d_ + 512);                      \
  }

  // ds_read: logical k-slot = lane>>4, row = base + frow;
  // physical slot = (lane>>4) ^ ((frow>>1)&3)
  const int frow = lane & 15;
  const int colw = (((lane >> 4) ^ ((frow >> 1) & 3)) << 3);  // u16

  f32x4 acc[8][4] = {};

  const int NT = K >> 5;
  // prologue: stage tiles 0,1,2 (12 gloads/wave)
  STG_A(0); STG_B(0);
  STG_A(1); STG_B(1);
  STG_A(2); STG_B(2);

  for (int u = 0; u < NT; ++u) {
    // tile gate: exactly tile u's loads must have landed
    if (u <= NT - 3)      asm volatile("s_waitcnt vmcnt(8)" ::: "memory");
    else if (u == NT - 2) asm volatile("s_waitcnt vmcnt(4)" ::: "memory");
    else                  asm volatile("s_waitcnt vmcnt(0)" ::: "memory");
    __builtin_amdgcn_s_barrier();
    // stage tile u+3 into buffer (u+3)&3 == (u-1)&3 (dead past the barrier)
    if (u + 3 < NT) { STG_A(u + 3); STG_B(u + 3); }

    const u16* LA = &lds_[u & 3][0][0][0];
    const u16* LB = &lds_[u & 3][1][0][0];
    bf16x8 a0[4], b0[4], a1[4];
    // ---- ph0 (rows wr*128 .. +64); compiler inserts counted lgkmcnt
#pragma unroll
    for (int i = 0; i < 4; ++i)
      a0[i] = *reinterpret_cast<const bf16x8*>(&LA[(wr * 128 + i * 16 + frow) * 32 + colw]);
#pragma unroll
    for (int i = 0; i < 4; ++i)
      b0[i] = *reinterpret_cast<const bf16x8*>(&LB[(wc * 64 + i * 16 + frow) * 32 + colw]);
    __builtin_amdgcn_s_setprio(1);
#pragma unroll
    for (int i = 0; i < 4; ++i)
#pragma unroll
      for (int j = 0; j < 4; ++j)
        acc[i][j] = __builtin_amdgcn_mfma_f32_16x16x32_bf16(a0[i], b0[j], acc[i][j], 0, 0, 0);
    __builtin_amdgcn_s_setprio(0);
    // ---- ph1 (rows wr*128+64 .. +128; B regs reused)
#pragma unroll
    for (int i = 0; i < 4; ++i)
      a1[i] = *reinterpret_cast<const bf16x8*>(&LA[(wr * 128 + 64 + i * 16 + frow) * 32 + colw]);
    __builtin_amdgcn_s_setprio(1);
#pragma unroll
    for (int i = 0; i < 4; ++i)
#pragma unroll
      for (int j = 0; j < 4; ++j)
        acc[4 + i][j] = __builtin_amdgcn_mfma_f32_16x16x32_bf16(a1[i], b0[j], acc[4 + i][j], 0, 0, 0);
    __builtin_amdgcn_s_setprio(0);
  }

  // epilogue: C/D col=lane&15, row=(lane>>4)*4+reg
  const int er = (lane >> 4) << 2;
  const int ec = lane & 15;
#pragma unroll
  for (int mf = 0; mf < 8; ++mf) {
#pragma unroll
    for (int r = 0; r < 4; ++r) {
      const size_t row = (size_t)(bm + wr * 128 + mf * 16 + er + r);
      float rscale = 1.f;
      if constexpr (EPI == 3) rscale = RS[row];
#pragma unroll
      for (int nf = 0; nf < 4; ++nf) {
        const size_t col = (size_t)(bn + wc * 64 + nf * 16 + ec);
        const size_t idx = row * (size_t)N + col;
        const float val = acc[mf][nf][r];
        if constexpr (EPI == 0) {
          ((u16*)Cv)[idx] = f2bf(val);
        } else {
          ((float*)Cv)[idx] = val * rscale;
        }
      }
    }
  }
#undef STG_A
#undef STG_B
}

// ---------------- chunked gated scan ----------------
__global__ __launch_bounds__(256) void scan_a(const u16* __restrict__ a,
                                              const u16* __restrict__ v,
                                              float* __restrict__ S_p,
                                              float* __restrict__ S_h) {
  const int idx = blockIdx.x * 256 + threadIdx.x;
  const int ch8 = idx & 511;
  const int c = (idx >> 9) & 31;
  const int b = idx >> 14;
  const int ch = ch8 << 3;
  size_t off = ((size_t)(b * 2048 + c * 64)) * 4096 + ch;
  float h[8], p[8];
#pragma unroll
  for (int j = 0; j < 8; ++j) { h[j] = 0.f; p[j] = 1.f; }
  for (int t = 0; t < 64; ++t) {
    u16x8 ua = *(const u16x8*)&a[off];
    u16x8 uv = *(const u16x8*)&v[off];
#pragma unroll
    for (int j = 0; j < 8; ++j) {
      float at = bf2f(ua[j]);
      h[j] = at * h[j] + (1.f - at) * bf2f(uv[j]);
      p[j] *= at;
    }
    off += 4096;
  }
  size_t so = (size_t)(b * 32 + c) * 4096 + ch;
#pragma unroll
  for (int j = 0; j < 8; ++j) { S_p[so + j] = p[j]; S_h[so + j] = h[j]; }
}

__global__ __launch_bounds__(256) void scan_b(const float* __restrict__ S_p,
                                              const float* __restrict__ S_h,
                                              float* __restrict__ Hin) {
  const int idx = blockIdx.x * 256 + threadIdx.x;
  const int b = idx >> 12;
  const int ch = idx & 4095;
  float H = 0.f;
  for (int c = 0; c < 32; ++c) {
    size_t so = (size_t)(b * 32 + c) * 4096 + ch;
    Hin[so] = H;
    H = S_p[so] * H + S_h[so];
  }
}

__global__ __launch_bounds__(256) void scan_c(const u16* __restrict__ a,
                                              u16* __restrict__ vh,
                                              const float* __restrict__ Hin) {
  const int idx = blockIdx.x * 256 + threadIdx.x;
  const int ch8 = idx & 511;
  const int c = (idx >> 9) & 31;
  const int b = idx >> 14;
  const int ch = ch8 << 3;
  size_t so = (size_t)(b * 32 + c) * 4096 + ch;
  float h[8];
#pragma unroll
  for (int j = 0; j < 8; ++j) h[j] = Hin[so + j];
  size_t off = ((size_t)(b * 2048 + c * 64)) * 4096 + ch;
  for (int t = 0; t < 64; ++t) {
    u16x8 ua = *(const u16x8*)&a[off];
    u16x8 uv = *(const u16x8*)&vh[off];
    u16x8 out;
#pragma unroll
    for (int j = 0; j < 8; ++j) {
      float at = bf2f(ua[j]);
      h[j] = at * h[j] + (1.f - at) * bf2f(uv[j]);
      out[j] = f2bf(h[j]);
    }
    *(u16x8*)&vh[off] = out;
    off += 4096;
  }
}

// ---------------- per-row rsqrt(mean(g^2)+eps) -> RS[8192] ----------------
__global__ __launch_bounds__(256) void rowssq(const u16* __restrict__ g,
                                              float* __restrict__ rs) {
  const size_t base = (size_t)blockIdx.x * 4096;
  const int tid = threadIdx.x;
  const int c0 = tid * 16;
  u16 vals[16];
  *(u32x4*)&vals[0] = *(const u32x4*)&g[base + c0];
  *(u32x4*)&vals[8] = *(const u32x4*)&g[base + c0 + 8];
  float s = 0.f;
#pragma unroll
  for (int i = 0; i < 16; ++i) {
    float f = bf2f(vals[i]);
    s += f * f;
  }
#pragma unroll
  for (int o = 32; o > 0; o >>= 1) s += __shfl_down(s, o, 64);
  __shared__ float red[4];
  if ((tid & 63) == 0) red[tid >> 6] = s;
  __syncthreads();
  if (tid == 0) {
    float tot = red[0] + red[1] + red[2] + red[3];
    rs[blockIdx.x] = rsqrtf(tot * (1.0f / 4096.0f) + 1e-6f);
  }
}

extern "C" void kernel_launch(void* const* d_in, const int* in_sizes, int n_in,
                              void* d_out, int out_size, void* d_ws, size_t ws_size,
                              hipStream_t stream) {
  const float* x   = (const float*)d_in[0];
  const float* Wq1 = (const float*)d_in[1];
  const float* Wq2 = (const float*)d_in[2];
  const float* Wk1 = (const float*)d_in[3];
  const float* Wk2 = (const float*)d_in[4];
  const float* Wv  = (const float*)d_in[5];
  const float* Wo  = (const float*)d_in[6];
  const float* nw  = (const float*)d_in[7];

  char* ws = (char*)d_ws;
  // R0 [0,64M): X + WVT, overlaid later by AA (a)
  u16* X     = (u16*)(ws + 0);           // 8192x2048
  u16* WVT   = (u16*)(ws + 33554432);    // 4096x2048
  u16* AA    = (u16*)(ws + 0);           // 8192x4096 overlay
  // R1
  u16* VV    = (u16*)(ws + 67108864);    // 8192x4096 (v -> h -> g in place)
  // R2
  u16* T12   = (u16*)(ws + 134217728);   // 8192x256 (q1 | k1)
  u16* WQK1T = (u16*)(ws + 138412032);   // 256x2048
  u16* WQ2T  = (u16*)(ws + 139460608);   // 4096x128
  u16* WK2T  = (u16*)(ws + 140509184);   // 4096x128
  u16* WOT   = (u16*)(ws + 141557760);   // 2048x4096 (nw folded)
  float* S_P = (float*)(ws + 158334976);
  float* S_H = (float*)(ws + 160432128);
  float* HIN = (float*)(ws + 162529280);
  float* RS  = (float*)(ws + 164626432); // 8192 f32; end ~157 MB

  cast_kernel<<<16384, 256, 0, stream>>>(x, X, 16777216L);
  transpose_cast<<<dim3(4, 64),   dim3(32, 8), 0, stream>>>(Wq1, WQK1T, 2048, 128);
  transpose_cast<<<dim3(4, 64),   dim3(32, 8), 0, stream>>>(Wk1, WQK1T + 128 * 2048, 2048, 128);
  transpose_cast<<<dim3(128, 4),  dim3(32, 8), 0, stream>>>(Wq2, WQ2T, 128, 4096);
  transpose_cast<<<dim3(128, 4),  dim3(32, 8), 0, stream>>>(Wk2, WK2T, 128, 4096);
  transpose_cast<<<dim3(128, 64), dim3(32, 8), 0, stream>>>(Wv, WVT, 2048, 4096);
  transpose_cast_nw<<<dim3(64, 128), dim3(32, 8), 0, stream>>>(Wo, nw, WOT, 4096, 2048);

  // q1|k1 fused: T12 = X @ [Wq1 Wk1]
  gemm_bt<0><<<dim3(64, 2), 256, 0, stream>>>(X, 2048, WQK1T, T12, 8192, 256, 2048);
  // v = X @ Wv  (256^2 4-buffer pipelined; nby = N/256 = 16)
  gemm8<0><<<512, 512, 0, stream>>>(X, WVT, VV, nullptr, 8192, 4096, 2048, 16);
  // a = sig(sig(k1 @ Wk2)) into R0 overlay (X/WVT dead)
  gemm_bt<2><<<dim3(64, 32), 256, 0, stream>>>(T12 + 128, 256, WK2T, AA, 8192, 4096, 128);

  // chunked scan: VV := h (in place)
  scan_a<<<256, 256, 0, stream>>>(AA, VV, S_P, S_H);
  scan_b<<<64, 256, 0, stream>>>(S_P, S_H, HIN);
  scan_c<<<256, 256, 0, stream>>>(AA, VV, HIN);

  // g = silu(q1 @ Wq2) * h, in place over VV
  gemm_bt<4><<<dim3(64, 32), 256, 0, stream>>>(T12, 256, WQ2T, VV, 8192, 4096, 128);

  // row scales; then out = (g * RS[row]) @ (Wo*nw)   (nby = 2048/256 = 8)
  rowssq<<<8192, 256, 0, stream>>>(VV, RS);
  gemm8<3><<<256, 512, 0, stream>>>(VV, WOT, d_out, RS, 8192, 2048, 4096, 8);
}

// Round 9
// 657.281 us; speedup vs baseline: 1.2807x; 1.0031x over previous
//
#include <hip/hip_runtime.h>

// Hgru1: q=silu((x@Wq1)@Wq2); a=sig(sig((x@Wk1)@Wk2)); v=x@Wv;
// h_t = a_t h_{t-1} + (1-a_t) v_t ; out = RMSNorm(q*h)*nw @ Wo
// B=4 N=2048 E=2048 HD=128 E2=4096, M=B*N=8192

typedef unsigned short u16;
typedef __attribute__((ext_vector_type(4))) float f32x4;
typedef __attribute__((ext_vector_type(8))) __bf16 bf16x8;
typedef __attribute__((ext_vector_type(8))) u16 u16x8;
typedef __attribute__((ext_vector_type(4))) unsigned int u32x4;

__device__ __forceinline__ float bf2f(u16 u) {
  unsigned int i = ((unsigned int)u) << 16;
  return __builtin_bit_cast(float, i);
}
__device__ __forceinline__ u16 f2bf(float f) {
  unsigned int i = __builtin_bit_cast(unsigned int, f);
  i += 0x7fffu + ((i >> 16) & 1u);   // RNE
  return (u16)(i >> 16);
}

__device__ __forceinline__ void gload_lds16(const u16* g, u16* l) {
  __builtin_amdgcn_global_load_lds(
      (const __attribute__((address_space(1))) void*)g,
      (__attribute__((address_space(3))) void*)l, 16, 0, 0);
}

// ---------------- casts ----------------
__global__ __launch_bounds__(256) void cast_kernel(const float* __restrict__ in,
                                                   u16* __restrict__ out, long n) {
  long i = ((long)blockIdx.x * 256 + threadIdx.x) * 4;
  if (i >= n) return;
  f32x4 fv = *(const f32x4*)&in[i];
  unsigned long long pk = (unsigned long long)f2bf(fv[0]) |
                          ((unsigned long long)f2bf(fv[1]) << 16) |
                          ((unsigned long long)f2bf(fv[2]) << 32) |
                          ((unsigned long long)f2bf(fv[3]) << 48);
  *(unsigned long long*)&out[i] = pk;
}

// W [R][Cc] f32 -> WT [Cc][R] bf16   (grid: (Cc/32, R/32), block (32,8))
__global__ __launch_bounds__(256) void transpose_cast(const float* __restrict__ W,
                                                      u16* __restrict__ WT, int R, int Cc) {
  __shared__ float tile[32][33];
  const int tx = threadIdx.x, ty = threadIdx.y;
  const int x = blockIdx.x * 32 + tx;
  const int ybase = blockIdx.y * 32;
#pragma unroll
  for (int i = 0; i < 32; i += 8)
    tile[ty + i][tx] = W[(size_t)(ybase + ty + i) * Cc + x];
  __syncthreads();
  const int xt = ybase + tx;
  const int ytbase = blockIdx.x * 32;
#pragma unroll
  for (int i = 0; i < 32; i += 8)
    WT[(size_t)(ytbase + ty + i) * R + xt] = f2bf(tile[tx][ty + i]);
}

// Wo variant: WT[n][k] = Wo[k][n] * nw[k]  (folds RMSNorm weight into Wo)
__global__ __launch_bounds__(256) void transpose_cast_nw(const float* __restrict__ W,
                                                         const float* __restrict__ nw,
                                                         u16* __restrict__ WT, int R, int Cc) {
  __shared__ float tile[32][33];
  const int tx = threadIdx.x, ty = threadIdx.y;
  const int x = blockIdx.x * 32 + tx;
  const int ybase = blockIdx.y * 32;
#pragma unroll
  for (int i = 0; i < 32; i += 8)
    tile[ty + i][tx] = W[(size_t)(ybase + ty + i) * Cc + x];
  __syncthreads();
  const int xt = ybase + tx;           // k index
  const float s = nw[xt];
  const int ytbase = blockIdx.x * 32;
#pragma unroll
  for (int i = 0; i < 32; i += 8)
    WT[(size_t)(ytbase + ty + i) * R + xt] = f2bf(tile[tx][ty + i] * s);
}

// ---------------- 128x128 GEMM (2-barrier, for K=128/N=256 cases) ----------
// C[m][n] = sum_k A[m][k]*BT[n][k]; A row stride = lda.
// EPI: 0 bf16 store; 2 sig(sig)->bf16; 4 in-place g = silu(acc)*h
template <int EPI>
__global__ __launch_bounds__(256) void gemm_bt(const u16* __restrict__ A, int lda,
                                               const u16* __restrict__ BT,
                                               void* __restrict__ Cv,
                                               int M, int N, int K) {
  __shared__ __align__(16) u16 As[4096];
  __shared__ __align__(16) u16 Bs[4096];
  const int tid = threadIdx.x;
  const int lane = tid & 63;
  const int wid = tid >> 6;
  const int wr = wid >> 1, wc = wid & 1;
  const long bm = (long)blockIdx.x * 128;
  const long bn = (long)blockIdx.y * 128;

  const int sm = lane >> 2;
  const int sk = (lane & 3) << 3;
  const u16* Ag0 = A + (size_t)(bm + wid * 16 + sm) * lda + sk;
  const u16* Ag1 = A + (size_t)(bm + 64 + wid * 16 + sm) * lda + sk;
  const u16* Bg0 = BT + (size_t)(bn + wid * 16 + sm) * K + sk;
  const u16* Bg1 = BT + (size_t)(bn + 64 + wid * 16 + sm) * K + sk;
  u16* As0 = As + wid * 512;
  u16* As1 = As + 2048 + wid * 512;
  u16* Bs0 = Bs + wid * 512;
  u16* Bs1 = Bs + 2048 + wid * 512;

  f32x4 acc[4][4] = {};

  const int fra = wr * 64 + (lane & 15);
  const int frb = wc * 64 + (lane & 15);
  const int kg = (lane >> 4) << 3;

  for (int kk = 0; kk < K; kk += 32) {
    gload_lds16(Ag0 + kk, As0);
    gload_lds16(Ag1 + kk, As1);
    gload_lds16(Bg0 + kk, Bs0);
    gload_lds16(Bg1 + kk, Bs1);
    __syncthreads();
    bf16x8 af[4], bv[4];
#pragma unroll
    for (int mi = 0; mi < 4; ++mi)
      af[mi] = *reinterpret_cast<const bf16x8*>(&As[(fra + mi * 16) * 32 + kg]);
#pragma unroll
    for (int ni = 0; ni < 4; ++ni)
      bv[ni] = *reinterpret_cast<const bf16x8*>(&Bs[(frb + ni * 16) * 32 + kg]);
#pragma unroll
    for (int mi = 0; mi < 4; ++mi) {
#pragma unroll
      for (int ni = 0; ni < 4; ++ni)
        acc[mi][ni] =
            __builtin_amdgcn_mfma_f32_16x16x32_bf16(af[mi], bv[ni], acc[mi][ni], 0, 0, 0);
    }
    __syncthreads();
  }

  const int r0 = wr * 64 + ((lane >> 4) << 2);
  const int c0 = wc * 64 + (lane & 15);
#pragma unroll
  for (int mi = 0; mi < 4; ++mi) {
#pragma unroll
    for (int ni = 0; ni < 4; ++ni) {
#pragma unroll
      for (int r = 0; r < 4; ++r) {
        size_t row = (size_t)(bm + r0 + mi * 16 + r);
        size_t col = (size_t)(bn + c0 + ni * 16);
        size_t idx = row * (size_t)N + col;
        float val = acc[mi][ni][r];
        if constexpr (EPI == 0) {
          ((u16*)Cv)[idx] = f2bf(val);
        } else if constexpr (EPI == 2) {  // a = sigmoid(sigmoid(raw))
          float f = 1.f / (1.f + __expf(-val));
          float aa = 1.f / (1.f + __expf(-f));
          ((u16*)Cv)[idx] = f2bf(aa);
        } else {  // EPI == 4: g = silu(acc) * h, in place over h
          float hv = bf2f(((u16*)Cv)[idx]);
          float s = 1.f / (1.f + __expf(-val));
          ((u16*)Cv)[idx] = f2bf(val * s * hv);
        }
      }
    }
  }
}

// ---------------- 256x256 GEMM, m201-style phase-pair schedule -------------
// BK=32, 4 LDS buffers [4][2][256][32] (128 KiB), 8 waves (2Mx4N), per-wave
// C = 128x64 (acc[8][4]).  Per K-tile: tile-top counted vmcnt + barrier, then
// two phase-pairs in the m201 template shape:
//   ph_a: {ds_read A-mh0(4)+B(4); STG_A(u+3); barrier; lgkmcnt(0);
//          setprio(1); 16 MFMA; setprio(0); barrier}
//   ph_b: {ds_read A-mh1(4);      STG_B(u+3); barrier; lgkmcnt(0);
//          setprio(1); 16 MFMA; setprio(0)}
// Staging sits between reads and the MFMA-gate barrier (fine interleave,
// m196 lever); buffer (u+3)&3 == (u-1)&3 is dead past the tile-top barrier.
// vmcnt counted: 8 (u<=NT-3), 4 (u==NT-2), 0 (u==NT-1) — never drained mid-loop.
// Swizzle: 16B slot' = slot ^ ((row>>1)&3), inverse-swizzled global source +
// swizzled ds_read (bank-conflict-free, verified r7/r8: SQ_LDS_BANK_CONFLICT=0).
// EPI: 0 = bf16 store; 3 = f32 store * RS[row]
template <int EPI>
__global__ __launch_bounds__(512, 2) void gemm8(const u16* __restrict__ A,
                                                const u16* __restrict__ BT,
                                                void* __restrict__ Cv,
                                                const float* __restrict__ RS,
                                                int M, int N, int K, int nby) {
  __shared__ __align__(16) u16 lds_[4][2][256][32];  // [buf][A/B][row][col]
  const int tid = threadIdx.x;
  const int lane = tid & 63;
  const int w = tid >> 6;         // 0..7
  const int wr = w >> 2;          // M half
  const int wc = w & 3;           // N quarter

  // bijective XCD swizzle; M-stripes per XCD (A-chunk fits 4MiB L2)
  const int nwg = gridDim.x;
  const int bid = blockIdx.x;
  const int swz = (bid & 7) * (nwg >> 3) + (bid >> 3);
  const long bm = (long)(swz / nby) * 256;
  const long bn = (long)(swz % nby) * 256;

  // staging: wave w owns rows [32w,32w+32); 2 gloads (16 rows each) per
  // matrix per tile. Linear LDS dest; inverse-swizzled global source:
  // lane l -> row l>>2, phys slot l&3 holds logical slot (l&3)^((l>>3)&3).
  const int srow = lane >> 2;
  const int scol = ((lane & 3) ^ ((lane >> 3) & 3)) << 3;  // u16
  const u16* Ag = A + (size_t)(bm + w * 32 + srow) * K + scol;
  const u16* Bg = BT + (size_t)(bn + w * 32 + srow) * K + scol;

#define STG_A(t)                                                     \
  {                                                                  \
    const u16* s_ = Ag + (size_t)(t) * 32;                           \
    u16* d_ = &lds_[(t) & 3][0][w * 32][0];                          \
    gload_lds16(s_, d_);                                             \
    gload_lds16(s_ + (size_t)16 * K, d_ + 512);                      \
  }
#define STG_B(t)                                                     \
  {                                                                  \
    const u16* s_ = Bg + (size_t)(t) * 32;                           \
    u16* d_ = &lds_[(t) & 3][1][w * 32][0];                          \
    gload_lds16(s_, d_);                                             \
    gload_lds16(s_ + (size_t)16 * K, d_ + 512);                      \
  }

  // ds_read: logical k-slot = lane>>4, row = base + frow;
  // physical slot = (lane>>4) ^ ((frow>>1)&3)
  const int frow = lane & 15;
  const int colw = (((lane >> 4) ^ ((frow >> 1) & 3)) << 3);  // u16

  f32x4 acc[8][4] = {};

  const int NT = K >> 5;
  // prologue: stage tiles 0,1,2 (12 gloads/wave)
  STG_A(0); STG_B(0);
  STG_A(1); STG_B(1);
  STG_A(2); STG_B(2);

  for (int u = 0; u < NT; ++u) {
    // tile gate: exactly tile u's loads must have landed (counted, never 0 mid-loop)
    if (u <= NT - 3)      asm volatile("s_waitcnt vmcnt(8)" ::: "memory");
    else if (u == NT - 2) asm volatile("s_waitcnt vmcnt(4)" ::: "memory");
    else                  asm volatile("s_waitcnt vmcnt(0)" ::: "memory");
    __builtin_amdgcn_s_barrier();

    const u16* LA = &lds_[u & 3][0][0][0];
    const u16* LB = &lds_[u & 3][1][0][0];
    bf16x8 a0[4], b0[4], a1[4];
    // ---- ph_a: read A-mh0 + B, stage A(u+3), barrier, lgkm, MFMA
#pragma unroll
    for (int i = 0; i < 4; ++i)
      a0[i] = *reinterpret_cast<const bf16x8*>(&LA[(wr * 128 + i * 16 + frow) * 32 + colw]);
#pragma unroll
    for (int i = 0; i < 4; ++i)
      b0[i] = *reinterpret_cast<const bf16x8*>(&LB[(wc * 64 + i * 16 + frow) * 32 + colw]);
    if (u + 3 < NT) STG_A(u + 3);
    __builtin_amdgcn_s_barrier();
    asm volatile("s_waitcnt lgkmcnt(0)" ::: "memory");
    __builtin_amdgcn_s_setprio(1);
#pragma unroll
    for (int i = 0; i < 4; ++i)
#pragma unroll
      for (int j = 0; j < 4; ++j)
        acc[i][j] = __builtin_amdgcn_mfma_f32_16x16x32_bf16(a0[i], b0[j], acc[i][j], 0, 0, 0);
    __builtin_amdgcn_s_setprio(0);
    __builtin_amdgcn_s_barrier();
    // ---- ph_b: read A-mh1, stage B(u+3), barrier, lgkm, MFMA (B regs reused)
#pragma unroll
    for (int i = 0; i < 4; ++i)
      a1[i] = *reinterpret_cast<const bf16x8*>(&LA[(wr * 128 + 64 + i * 16 + frow) * 32 + colw]);
    if (u + 3 < NT) STG_B(u + 3);
    __builtin_amdgcn_s_barrier();
    asm volatile("s_waitcnt lgkmcnt(0)" ::: "memory");
    __builtin_amdgcn_s_setprio(1);
#pragma unroll
    for (int i = 0; i < 4; ++i)
#pragma unroll
      for (int j = 0; j < 4; ++j)
        acc[4 + i][j] = __builtin_amdgcn_mfma_f32_16x16x32_bf16(a1[i], b0[j], acc[4 + i][j], 0, 0, 0);
    __builtin_amdgcn_s_setprio(0);
  }

  // epilogue: C/D col=lane&15, row=(lane>>4)*4+reg
  const int er = (lane >> 4) << 2;
  const int ec = lane & 15;
#pragma unroll
  for (int mf = 0; mf < 8; ++mf) {
#pragma unroll
    for (int r = 0; r < 4; ++r) {
      const size_t row = (size_t)(bm + wr * 128 + mf * 16 + er + r);
      float rscale = 1.f;
      if constexpr (EPI == 3) rscale = RS[row];
#pragma unroll
      for (int nf = 0; nf < 4; ++nf) {
        const size_t col = (size_t)(bn + wc * 64 + nf * 16 + ec);
        const size_t idx = row * (size_t)N + col;
        const float val = acc[mf][nf][r];
        if constexpr (EPI == 0) {
          ((u16*)Cv)[idx] = f2bf(val);
        } else {
          ((float*)Cv)[idx] = val * rscale;
        }
      }
    }
  }
#undef STG_A
#undef STG_B
}

// ---------------- chunked gated scan ----------------
__global__ __launch_bounds__(256) void scan_a(const u16* __restrict__ a,
                                              const u16* __restrict__ v,
                                              float* __restrict__ S_p,
                                              float* __restrict__ S_h) {
  const int idx = blockIdx.x * 256 + threadIdx.x;
  const int ch8 = idx & 511;
  const int c = (idx >> 9) & 31;
  const int b = idx >> 14;
  const int ch = ch8 << 3;
  size_t off = ((size_t)(b * 2048 + c * 64)) * 4096 + ch;
  float h[8], p[8];
#pragma unroll
  for (int j = 0; j < 8; ++j) { h[j] = 0.f; p[j] = 1.f; }
  for (int t = 0; t < 64; ++t) {
    u16x8 ua = *(const u16x8*)&a[off];
    u16x8 uv = *(const u16x8*)&v[off];
#pragma unroll
    for (int j = 0; j < 8; ++j) {
      float at = bf2f(ua[j]);
      h[j] = at * h[j] + (1.f - at) * bf2f(uv[j]);
      p[j] *= at;
    }
    off += 4096;
  }
  size_t so = (size_t)(b * 32 + c) * 4096 + ch;
#pragma unroll
  for (int j = 0; j < 8; ++j) { S_p[so + j] = p[j]; S_h[so + j] = h[j]; }
}

__global__ __launch_bounds__(256) void scan_b(const float* __restrict__ S_p,
                                              const float* __restrict__ S_h,
                                              float* __restrict__ Hin) {
  const int idx = blockIdx.x * 256 + threadIdx.x;
  const int b = idx >> 12;
  const int ch = idx & 4095;
  float H = 0.f;
  for (int c = 0; c < 32; ++c) {
    size_t so = (size_t)(b * 32 + c) * 4096 + ch;
    Hin[so] = H;
    H = S_p[so] * H + S_h[so];
  }
}

__global__ __launch_bounds__(256) void scan_c(const u16* __restrict__ a,
                                              u16* __restrict__ vh,
                                              const float* __restrict__ Hin) {
  const int idx = blockIdx.x * 256 + threadIdx.x;
  const int ch8 = idx & 511;
  const int c = (idx >> 9) & 31;
  const int b = idx >> 14;
  const int ch = ch8 << 3;
  size_t so = (size_t)(b * 32 + c) * 4096 + ch;
  float h[8];
#pragma unroll
  for (int j = 0; j < 8; ++j) h[j] = Hin[so + j];
  size_t off = ((size_t)(b * 2048 + c * 64)) * 4096 + ch;
  for (int t = 0; t < 64; ++t) {
    u16x8 ua = *(const u16x8*)&a[off];
    u16x8 uv = *(const u16x8*)&vh[off];
    u16x8 out;
#pragma unroll
    for (int j = 0; j < 8; ++j) {
      float at = bf2f(ua[j]);
      h[j] = at * h[j] + (1.f - at) * bf2f(uv[j]);
      out[j] = f2bf(h[j]);
    }
    *(u16x8*)&vh[off] = out;
    off += 4096;
  }
}

// ---------------- per-row rsqrt(mean(g^2)+eps) -> RS[8192] ----------------
__global__ __launch_bounds__(256) void rowssq(const u16* __restrict__ g,
                                              float* __restrict__ rs) {
  const size_t base = (size_t)blockIdx.x * 4096;
  const int tid = threadIdx.x;
  const int c0 = tid * 16;
  u16 vals[16];
  *(u32x4*)&vals[0] = *(const u32x4*)&g[base + c0];
  *(u32x4*)&vals[8] = *(const u32x4*)&g[base + c0 + 8];
  float s = 0.f;
#pragma unroll
  for (int i = 0; i < 16; ++i) {
    float f = bf2f(vals[i]);
    s += f * f;
  }
#pragma unroll
  for (int o = 32; o > 0; o >>= 1) s += __shfl_down(s, o, 64);
  __shared__ float red[4];
  if ((tid & 63) == 0) red[tid >> 6] = s;
  __syncthreads();
  if (tid == 0) {
    float tot = red[0] + red[1] + red[2] + red[3];
    rs[blockIdx.x] = rsqrtf(tot * (1.0f / 4096.0f) + 1e-6f);
  }
}

extern "C" void kernel_launch(void* const* d_in, const int* in_sizes, int n_in,
                              void* d_out, int out_size, void* d_ws, size_t ws_size,
                              hipStream_t stream) {
  const float* x   = (const float*)d_in[0];
  const float* Wq1 = (const float*)d_in[1];
  const float* Wq2 = (const float*)d_in[2];
  const float* Wk1 = (const float*)d_in[3];
  const float* Wk2 = (const float*)d_in[4];
  const float* Wv  = (const float*)d_in[5];
  const float* Wo  = (const float*)d_in[6];
  const float* nw  = (const float*)d_in[7];

  char* ws = (char*)d_ws;
  // R0 [0,64M): X + WVT, overlaid later by AA (a)
  u16* X     = (u16*)(ws + 0);           // 8192x2048
  u16* WVT   = (u16*)(ws + 33554432);    // 4096x2048
  u16* AA    = (u16*)(ws + 0);           // 8192x4096 overlay
  // R1
  u16* VV    = (u16*)(ws + 67108864);    // 8192x4096 (v -> h -> g in place)
  // R2
  u16* T12   = (u16*)(ws + 134217728);   // 8192x256 (q1 | k1)
  u16* WQK1T = (u16*)(ws + 138412032);   // 256x2048
  u16* WQ2T  = (u16*)(ws + 139460608);   // 4096x128
  u16* WK2T  = (u16*)(ws + 140509184);   // 4096x128
  u16* WOT   = (u16*)(ws + 141557760);   // 2048x4096 (nw folded)
  float* S_P = (float*)(ws + 158334976);
  float* S_H = (float*)(ws + 160432128);
  float* HIN = (float*)(ws + 162529280);
  float* RS  = (float*)(ws + 164626432); // 8192 f32; end ~157 MB

  cast_kernel<<<16384, 256, 0, stream>>>(x, X, 16777216L);
  transpose_cast<<<dim3(4, 64),   dim3(32, 8), 0, stream>>>(Wq1, WQK1T, 2048, 128);
  transpose_cast<<<dim3(4, 64),   dim3(32, 8), 0, stream>>>(Wk1, WQK1T + 128 * 2048, 2048, 128);
  transpose_cast<<<dim3(128, 4),  dim3(32, 8), 0, stream>>>(Wq2, WQ2T, 128, 4096);
  transpose_cast<<<dim3(128, 4),  dim3(32, 8), 0, stream>>>(Wk2, WK2T, 128, 4096);
  transpose_cast<<<dim3(128, 64), dim3(32, 8), 0, stream>>>(Wv, WVT, 2048, 4096);
  transpose_cast_nw<<<dim3(64, 128), dim3(32, 8), 0, stream>>>(Wo, nw, WOT, 4096, 2048);

  // q1|k1 fused: T12 = X @ [Wq1 Wk1]
  gemm_bt<0><<<dim3(64, 2), 256, 0, stream>>>(X, 2048, WQK1T, T12, 8192, 256, 2048);
  // v = X @ Wv  (256^2 phase-pair pipelined; nby = N/256 = 16)
  gemm8<0><<<512, 512, 0, stream>>>(X, WVT, VV, nullptr, 8192, 4096, 2048, 16);
  // a = sig(sig(k1 @ Wk2)) into R0 overlay (X/WVT dead)
  gemm_bt<2><<<dim3(64, 32), 256, 0, stream>>>(T12 + 128, 256, WK2T, AA, 8192, 4096, 128);

  // chunked scan: VV := h (in place)
  scan_a<<<256, 256, 0, stream>>>(AA, VV, S_P, S_H);
  scan_b<<<64, 256, 0, stream>>>(S_P, S_H, HIN);
  scan_c<<<256, 256, 0, stream>>>(AA, VV, HIN);

  // g = silu(q1 @ Wq2) * h, in place over VV
  gemm_bt<4><<<dim3(64, 32), 256, 0, stream>>>(T12, 256, WQ2T, VV, 8192, 4096, 128);

  // row scales; then out = (g * RS[row]) @ (Wo*nw)   (nby = 2048/256 = 8)
  rowssq<<<8192, 256, 0, stream>>>(VV, RS);
  gemm8<3><<<256, 512, 0, stream>>>(VV, WOT, d_out, RS, 8192, 2048, 4096, 8);
}